// Round 9
// baseline (1530.525 us; speedup 1.0000x reference)
//
#include <hip/hip_runtime.h>

#define NB 4
#define NP 8192
#define NS 1024
#define NK 32
#define CNT_ALL 131072.0f   // NB*NS*NK

typedef unsigned long long u64;

template <int CTRL>
__device__ __forceinline__ u64 dpp_max_u64(u64 k)
{
    unsigned lo = (unsigned)k, hi = (unsigned)(k >> 32);
    unsigned olo = (unsigned)__builtin_amdgcn_update_dpp((int)lo, (int)lo, CTRL, 0xF, 0xF, false);
    unsigned ohi = (unsigned)__builtin_amdgcn_update_dpp((int)hi, (int)hi, CTRL, 0xF, 0xF, false);
    u64 o = ((u64)ohi << 32) | (u64)olo;
    return (o > k) ? o : k;
}

__device__ __forceinline__ unsigned expand10(unsigned v)
{
    v &= 1023u;
    v = (v | (v << 16)) & 0x030000FFu;
    v = (v | (v << 8))  & 0x0300F00Fu;
    v = (v | (v << 4))  & 0x030C30C3u;
    v = (v | (v << 2))  & 0x09249249u;
    return v;
}

// ---------------------------------------------------------------- FPS: Morton-bucketed lazy update
// One block (512 thr, 8 waves) per batch; block NB zeroes BN stat shards.
// One-time: bitonic-sort (morton<<13|idx) in LDS; thread t owns 16 consecutive
// sorted points (compact cell) in registers + its bounding sphere (m, r).
// Per iter: thread skips its 16-pt scan iff (|c-m|-r-1e-5)^2 >= M_t (triangle
// inequality, conservative margin >> f32 error) -> skipped min-updates are
// exact no-ops, dist stays bit-identical to brute force. Argmax key =
// (distbits | 8191-origidx | sortedidx) u64 -> numpy first-max tie-break holds
// regardless of ownership order. Wave reduce: 6-step u64 DPP; cross-wave: LDS
// keys (double-buffered, 1 barrier/iter) + 3-step DPP. Winner coords read from
// LDS float4 table (broadcast).
__global__ __launch_bounds__(512, 1) void fps_kernel(const float* __restrict__ xyz,
                                                     float* __restrict__ newxyz,
                                                     float* __restrict__ st)
{
#pragma clang fp contract(off)
    if (blockIdx.x >= NB) {
        for (int i = threadIdx.x; i < 4096; i += 512) st[i] = 0.f;
        return;
    }
    __shared__ __align__(16) char smem[131072 + 128];
    u64*    keys = (u64*)smem;                       // sort scratch (dies after init)
    float4* s_p4 = (float4*)smem;                    // sorted coords (lives after)
    u64*    s_kv = (u64*)(smem + 131072);            // [2][8] cross-wave keys

    const int b = blockIdx.x;
    const int tid = threadIdx.x;
    const int lane = tid & 63;
    const int w = tid >> 6;                          // 8 waves
    const float* xb = xyz + (size_t)b * NP * 3;

    // ---- build morton keys (coalesced-ish reads)
    for (int k = 0; k < 16; ++k) {
        const int i = k * 512 + tid;
        const float x = xb[3 * i + 0], y = xb[3 * i + 1], z = xb[3 * i + 2];
        const unsigned ix = min((unsigned)(x * 1024.f), 1023u);
        const unsigned iy = min((unsigned)(y * 1024.f), 1023u);
        const unsigned iz = min((unsigned)(z * 1024.f), 1023u);
        const unsigned mc = (expand10(ix) << 2) | (expand10(iy) << 1) | expand10(iz);
        keys[i] = ((u64)mc << 13) | (unsigned)i;
    }
    __syncthreads();

    // ---- bitonic sort 8192 u64 (ascending)
    for (int k = 2; k <= NP; k <<= 1) {
        for (int j = k >> 1; j > 0; j >>= 1) {
#pragma unroll
            for (int u = 0; u < 8; ++u) {
                const int idx = u * 512 + tid;              // 0..4095
                const int low = idx & (j - 1);
                const int i = ((idx ^ low) << 1) | low;
                const int p = i | j;
                const bool up = ((i & k) == 0);
                const u64 a = keys[i], bb = keys[p];
                if ((a > bb) == up) { keys[i] = bb; keys[p] = a; }
            }
            __syncthreads();
        }
    }

    // ---- copy my 16 sorted keys to regs, then overwrite LDS with coords
    const int base = tid << 4;
    u64 myk[16];
#pragma unroll
    for (int j = 0; j < 16; ++j) myk[j] = keys[base + j];
    __syncthreads();                                  // all key reads done

    int oidx[16];
    float px[16], py[16], pz[16], dist[16];
#pragma unroll
    for (int j = 0; j < 16; ++j) {
        const int oi = (int)(myk[j] & 0x1FFFu);
        oidx[j] = oi;
        const float x = xb[3 * oi + 0], y = xb[3 * oi + 1], z = xb[3 * oi + 2];
        px[j] = x; py[j] = y; pz[j] = z;
        dist[j] = 1e10f;
        s_p4[base + j] = make_float4(x, y, z, 0.f);
    }
    __syncthreads();

    // ---- cell bounding sphere (conservative radius)
    float mnx = px[0], mxx = px[0], mny = py[0], mxy = py[0], mnz = pz[0], mxz = pz[0];
#pragma unroll
    for (int j = 1; j < 16; ++j) {
        mnx = fminf(mnx, px[j]); mxx = fmaxf(mxx, px[j]);
        mny = fminf(mny, py[j]); mxy = fmaxf(mxy, py[j]);
        mnz = fminf(mnz, pz[j]); mxz = fmaxf(mxz, pz[j]);
    }
    const float cmx = (mnx + mxx) * 0.5f;
    const float cmy = (mny + mxy) * 0.5f;
    const float cmz = (mnz + mxz) * 0.5f;
    float r2 = 0.f;
#pragma unroll
    for (int j = 0; j < 16; ++j) {
        const float dx = px[j] - cmx, dy = py[j] - cmy, dz = pz[j] - cmz;
        r2 = fmaxf(r2, dx * dx + dy * dy + dz * dz);
    }
    const float rb = sqrtf(r2) * 1.000002f + 1e-7f;

    // ---- main loop
    u64 key = ((u64)0x7F800000u << 26);               // M_t = +inf -> force first scan
    float cx = xb[0], cy = xb[1], cz = xb[2];
    float* ob = newxyz + (size_t)b * NS * 3;

    for (int it = 0; it < NS; ++it) {
        if (tid == 0) { ob[it * 3 + 0] = cx; ob[it * 3 + 1] = cy; ob[it * 3 + 2] = cz; }
        // conservative skip test (margin >> f32 error of scan math)
        const float ddx = cx - cmx, ddy = cy - cmy, ddz = cz - cmz;
        const float t = sqrtf(ddx * ddx + ddy * ddy + ddz * ddz);
        const float s = t - rb - 1e-5f;
        const float Mt = __uint_as_float((unsigned)(key >> 26));
        const bool skip = (s > 0.f) && (s * s >= Mt);
        if (!skip) {
            float bd = -1.f;
#pragma unroll
            for (int j = 0; j < 16; ++j) {
                const float dx = px[j] - cx, dy = py[j] - cy, dz = pz[j] - cz;
                const float d = (dx * dx + dy * dy) + dz * dz;   // numpy order, no fma
                const float dj = fminf(dist[j], d);
                dist[j] = dj;
                bd = fmaxf(bd, dj);
            }
            // recovery: among dist==bd pick smallest ORIGINAL index (numpy tie-break)
            int bo = 0x7FFFFFFF, bs = 0;
#pragma unroll
            for (int j = 0; j < 16; ++j) {
                const bool e = (dist[j] == bd) && (oidx[j] < bo);
                bo = e ? oidx[j] : bo;
                bs = e ? (base + j) : bs;
            }
            key = ((u64)__float_as_uint(bd) << 26) | ((u64)(unsigned)(8191 - bo) << 13)
                | (unsigned)bs;
        }
        // wave reduce (u64 max over 64 lanes)
        u64 wk = dpp_max_u64<0xB1>(key);
        wk = dpp_max_u64<0x4E>(wk);
        wk = dpp_max_u64<0x141>(wk);
        wk = dpp_max_u64<0x140>(wk);
        wk = dpp_max_u64<0x142>(wk);
        wk = dpp_max_u64<0x143>(wk);
        const unsigned wlo = (unsigned)__builtin_amdgcn_readlane((int)(unsigned)wk, 63);
        const unsigned whi = (unsigned)__builtin_amdgcn_readlane((int)(unsigned)(wk >> 32), 63);
        const u64 wmax = ((u64)whi << 32) | wlo;
        if (key == wmax) s_kv[(it & 1) * 8 + w] = wmax;   // exactly one lane/wave
        __syncthreads();
        u64 kv = s_kv[(it & 1) * 8 + (lane & 7)];
        kv = dpp_max_u64<0xB1>(kv);
        kv = dpp_max_u64<0x4E>(kv);
        kv = dpp_max_u64<0x141>(kv);              // every lane: max of the 8 wave keys
        const int fs = (int)(kv & 0x1FFFu);
        const float4 c4 = s_p4[fs];               // broadcast LDS read
        cx = c4.x; cy = c4.y; cz = c4.z;
    }
}

// compute BN scale/shift for channel c from 8-sharded sums
__device__ __forceinline__ void bn_coef(const float* __restrict__ sums,
                                        const float* __restrict__ sqs,
                                        const float* __restrict__ g,
                                        const float* __restrict__ be,
                                        int C, int c, float& sc, float& sh)
{
    float s = 0.f, q = 0.f;
#pragma unroll
    for (int k = 0; k < 8; ++k) { s += sums[k * C + c]; q += sqs[k * C + c]; }
    const float mean = s / CNT_ALL;
    const float var = q / CNT_ALL - mean * mean;
    sc = g[c] / sqrtf(var + 1e-5f);
    sh = be[c] - mean * sc;
}

// ---------------------------------------------------------------- Phase A: ball query + linear1 + stats1
__global__ __launch_bounds__(256) void phaseA_kernel(
    const float* __restrict__ xyz, const float* __restrict__ pts,
    const float* __restrict__ newxyz,
    const float* __restrict__ w1, const float* __restrict__ b1,
    float* __restrict__ y1, float* __restrict__ st)
{
    __shared__ int   s_ball[8][NK];
    __shared__ float s_feat[256][20];
    __shared__ float s_ps[256], s_pq[256];
    float* sums1 = st;
    float* sqs1 = st + 512;

    const int tid = threadIdx.x;
    const int bk = blockIdx.x;
    const int lane = tid & 63;
    const int wv_id = tid >> 6;

    const int b = (8 * bk) >> 10;
    const float* xb = xyz + (size_t)b * NP * 3;
    const float rr = (float)(0.2 * 0.2);
    for (int r = 0; r < 2; ++r) {
        const int lg = 2 * wv_id + r;
        const int sg = 8 * bk + lg;
        const float cx = newxyz[sg * 3 + 0];
        const float cy = newxyz[sg * 3 + 1];
        const float cz = newxyz[sg * 3 + 2];
        int cnt = 0;
        for (int base = 0; base < NP && cnt < NK; base += 64) {
            const int p = base + lane;
            float dx = xb[p * 3 + 0] - cx;
            float dy = xb[p * 3 + 1] - cy;
            float dz = xb[p * 3 + 2] - cz;
            float d = __fadd_rn(__fadd_rn(__fmul_rn(dx, dx), __fmul_rn(dy, dy)),
                                __fmul_rn(dz, dz));
            bool in = (d <= rr);
            unsigned long long mask = __ballot(in);
            int before = __popcll(mask & ((1ull << lane) - 1ull));
            int pos = cnt + before;
            if (in && pos < NK) s_ball[lg][pos] = p;
            cnt += (int)__popcll(mask);
        }
        cnt = min(cnt, NK);
        const int v0 = s_ball[lg][0];       // cnt >= 1 (centroid itself in-radius)
        if (lane < NK && lane >= cnt) s_ball[lg][lane] = v0;
    }
    __syncthreads();
    {   // stage features: thread t -> row t
        const int lg = tid >> 5, k = tid & 31;
        const int id = s_ball[lg][k];
        const int sg = 8 * bk + lg;
        const float* pp = xyz + ((size_t)b * NP + id) * 3;
        const float* cp = newxyz + (size_t)sg * 3;
        float* f = s_feat[tid];
        f[0] = pp[0] - cp[0];
        f[1] = pp[1] - cp[1];
        f[2] = pp[2] - cp[2];
        const float4* q4 = (const float4*)(pts + ((size_t)b * NP + id) * 16);
#pragma unroll
        for (int i = 0; i < 4; ++i) {
            float4 v = q4[i];
            f[3 + 4 * i + 0] = v.x; f[3 + 4 * i + 1] = v.y;
            f[3 + 4 * i + 2] = v.z; f[3 + 4 * i + 3] = v.w;
        }
        f[19] = 0.f;
    }
    __syncthreads();
    const int c = tid & 63, rg = tid >> 6;
    float wv[20];
#pragma unroll
    for (int j = 0; j < 19; ++j) wv[j] = w1[c * 19 + j];
    wv[19] = 0.f;
    const float bs = b1[c];
    float s = 0.f, q = 0.f;
    for (int r = 0; r < 64; ++r) {
        const int row = rg * 64 + r;
        const float4* f4 = (const float4*)s_feat[row];
        float acc = bs;
#pragma unroll
        for (int j4 = 0; j4 < 5; ++j4) {
            float4 v = f4[j4];
            acc += wv[4*j4+0]*v.x + wv[4*j4+1]*v.y + wv[4*j4+2]*v.z + wv[4*j4+3]*v.w;
        }
        y1[((size_t)256 * bk + row) * 64 + c] = acc;
        s += acc; q += acc * acc;
    }
    s_ps[tid] = s; s_pq[tid] = q;
    __syncthreads();
    if (rg == 0) {
        float ts = s_ps[c] + s_ps[64 + c] + s_ps[128 + c] + s_ps[192 + c];
        float tq = s_pq[c] + s_pq[64 + c] + s_pq[128 + c] + s_pq[192 + c];
        atomicAdd(&sums1[(bk & 7) * 64 + c], ts);
        atomicAdd(&sqs1[(bk & 7) * 64 + c], tq);
    }
}

// ---------------------------------------------------------------- Phase B: BN1+ReLU + linear2 + stats2
__global__ __launch_bounds__(256) void phaseB_kernel(
    const float* __restrict__ y1,
    const float* __restrict__ g1, const float* __restrict__ be1,
    const float* __restrict__ w2, const float* __restrict__ b2,
    float* __restrict__ y2, float* __restrict__ st)
{
    __shared__ float x_lds[128 * 64];       // 32 KB
    __shared__ float s_sc[64], s_sh[64];
    __shared__ float s_ps[256], s_pq[256];
    const float* sums1 = st;
    const float* sqs1 = st + 512;
    float* sums2 = st + 1024;
    float* sqs2 = st + 1536;

    const int tid = threadIdx.x;
    const int bk = blockIdx.x;
    if (tid < 64) {
        float sc, sh;
        bn_coef(sums1, sqs1, g1, be1, 64, tid, sc, sh);
        s_sc[tid] = sc; s_sh[tid] = sh;
    }
    __syncthreads();
    const int c = tid & 63, rg = tid >> 6;
    float wv[64];
#pragma unroll
    for (int j = 0; j < 64; ++j) wv[j] = w2[c * 64 + j];
    const float bs = b2[c];
    float s = 0.f, q = 0.f;
    for (int half = 0; half < 2; ++half) {
        const size_t row0 = (size_t)256 * bk + 128 * half;
        const float4* y1g = (const float4*)(y1 + row0 * 64);
        float4* xl4 = (float4*)x_lds;
#pragma unroll
        for (int i = 0; i < 8; ++i) {
            const int slot = i * 256 + tid;
            float4 v = y1g[slot];
            const int c4 = (slot & 15) * 4;
            float4 o;
            o.x = fmaxf(v.x * s_sc[c4+0] + s_sh[c4+0], 0.f);
            o.y = fmaxf(v.y * s_sc[c4+1] + s_sh[c4+1], 0.f);
            o.z = fmaxf(v.z * s_sc[c4+2] + s_sh[c4+2], 0.f);
            o.w = fmaxf(v.w * s_sc[c4+3] + s_sh[c4+3], 0.f);
            xl4[slot] = o;
        }
        __syncthreads();
        for (int r = 0; r < 32; ++r) {
            const int row = rg * 32 + r;
            const float4* x4 = (const float4*)(x_lds + row * 64);
            float acc = bs;
#pragma unroll
            for (int j4 = 0; j4 < 16; ++j4) {
                float4 v = x4[j4];
                acc += wv[4*j4+0]*v.x + wv[4*j4+1]*v.y + wv[4*j4+2]*v.z + wv[4*j4+3]*v.w;
            }
            y2[(row0 + row) * 64 + c] = acc;
            s += acc; q += acc * acc;
        }
        __syncthreads();
    }
    s_ps[tid] = s; s_pq[tid] = q;
    __syncthreads();
    if (rg == 0) {
        float ts = s_ps[c] + s_ps[64 + c] + s_ps[128 + c] + s_ps[192 + c];
        float tq = s_pq[c] + s_pq[64 + c] + s_pq[128 + c] + s_pq[192 + c];
        atomicAdd(&sums2[(bk & 7) * 64 + c], ts);
        atomicAdd(&sqs2[(bk & 7) * 64 + c], tq);
    }
}

// ---------------------------------------------------------------- Phase C: BN2+ReLU + linear3 + stats3
__global__ __launch_bounds__(256) void phaseC_kernel(
    const float* __restrict__ y2,
    const float* __restrict__ g2, const float* __restrict__ be2,
    const float* __restrict__ w3, const float* __restrict__ b3,
    float* __restrict__ st)
{
    __shared__ float s_x[NK * 64];          // 8 KB
    __shared__ float s_sc[64], s_sh[64];
    __shared__ float s_p3s[256], s_p3q[256];
    const float* sums2 = st + 1024;
    const float* sqs2 = st + 1536;
    float* sums3 = st + 2048;
    float* sqs3 = st + 3072;

    const int tid = threadIdx.x;
    const int bk = blockIdx.x;
    if (tid < 64) {
        float sc, sh;
        bn_coef(sums2, sqs2, g2, be2, 64, tid, sc, sh);
        s_sc[tid] = sc; s_sh[tid] = sh;
    }
    __syncthreads();
    const int c = tid & 127, rg = tid >> 7;
    float wv[64];
#pragma unroll
    for (int j = 0; j < 64; ++j) wv[j] = w3[c * 64 + j];
    const float bs = b3[c];
    float s = 0.f, q = 0.f;
    for (int gi = 0; gi < 8; ++gi) {
        const size_t grow0 = (size_t)256 * bk + 32 * gi;
        const float4* y2g = (const float4*)(y2 + grow0 * 64);
        float4* sx4 = (float4*)s_x;
#pragma unroll
        for (int i = 0; i < 2; ++i) {
            const int slot = i * 256 + tid;
            float4 v = y2g[slot];
            const int c4 = (slot & 15) * 4;
            float4 o;
            o.x = fmaxf(v.x * s_sc[c4+0] + s_sh[c4+0], 0.f);
            o.y = fmaxf(v.y * s_sc[c4+1] + s_sh[c4+1], 0.f);
            o.z = fmaxf(v.z * s_sc[c4+2] + s_sh[c4+2], 0.f);
            o.w = fmaxf(v.w * s_sc[c4+3] + s_sh[c4+3], 0.f);
            sx4[slot] = o;
        }
        __syncthreads();
        for (int r = 0; r < 16; ++r) {
            const int row = rg * 16 + r;
            const float4* x4 = (const float4*)(s_x + row * 64);
            float acc = bs;
#pragma unroll
            for (int j4 = 0; j4 < 16; ++j4) {
                float4 v = x4[j4];
                acc += wv[4*j4+0]*v.x + wv[4*j4+1]*v.y + wv[4*j4+2]*v.z + wv[4*j4+3]*v.w;
            }
            s += acc; q += acc * acc;
        }
        __syncthreads();
    }
    s_p3s[rg * 128 + c] = s; s_p3q[rg * 128 + c] = q;
    __syncthreads();
    if (rg == 0) {
        atomicAdd(&sums3[(bk & 7) * 128 + c], s_p3s[c] + s_p3s[128 + c]);
        atomicAdd(&sqs3[(bk & 7) * 128 + c], s_p3q[c] + s_p3q[128 + c]);
    }
}

// ---------------------------------------------------------------- Phase D: BN2+ReLU + linear3 + BN3 + ReLU + maxpool
__global__ __launch_bounds__(256) void phaseD_kernel(
    const float* __restrict__ y2,
    const float* __restrict__ g2, const float* __restrict__ be2,
    const float* __restrict__ g3, const float* __restrict__ be3,
    const float* __restrict__ w3, const float* __restrict__ b3,
    const float* __restrict__ st, float* __restrict__ out_np)
{
    __shared__ float s_x[NK * 64];
    __shared__ float s_sc[64], s_sh[64];
    __shared__ float s_fm[256];
    const float* sums2 = st + 1024;
    const float* sqs2 = st + 1536;
    const float* sums3 = st + 2048;
    const float* sqs3 = st + 3072;

    const int tid = threadIdx.x;
    const int bk = blockIdx.x;
    if (tid < 64) {
        float sc, sh;
        bn_coef(sums2, sqs2, g2, be2, 64, tid, sc, sh);
        s_sc[tid] = sc; s_sh[tid] = sh;
    }
    const int c = tid & 127, rg = tid >> 7;
    float sc3, sh3;
    bn_coef(sums3, sqs3, g3, be3, 128, c, sc3, sh3);
    __syncthreads();
    float wv[64];
#pragma unroll
    for (int j = 0; j < 64; ++j) wv[j] = w3[c * 64 + j];
    const float bs = b3[c];
    for (int gi = 0; gi < 8; ++gi) {
        const size_t grow0 = (size_t)256 * bk + 32 * gi;
        const float4* y2g = (const float4*)(y2 + grow0 * 64);
        float4* sx4 = (float4*)s_x;
#pragma unroll
        for (int i = 0; i < 2; ++i) {
            const int slot = i * 256 + tid;
            float4 v = y2g[slot];
            const int c4 = (slot & 15) * 4;
            float4 o;
            o.x = fmaxf(v.x * s_sc[c4+0] + s_sh[c4+0], 0.f);
            o.y = fmaxf(v.y * s_sc[c4+1] + s_sh[c4+1], 0.f);
            o.z = fmaxf(v.z * s_sc[c4+2] + s_sh[c4+2], 0.f);
            o.w = fmaxf(v.w * s_sc[c4+3] + s_sh[c4+3], 0.f);
            sx4[slot] = o;
        }
        __syncthreads();
        float m = 0.f;                       // relu >= 0
        for (int r = 0; r < 16; ++r) {
            const int row = rg * 16 + r;
            const float4* x4 = (const float4*)(s_x + row * 64);
            float acc = bs;
#pragma unroll
            for (int j4 = 0; j4 < 16; ++j4) {
                float4 v = x4[j4];
                acc += wv[4*j4+0]*v.x + wv[4*j4+1]*v.y + wv[4*j4+2]*v.z + wv[4*j4+3]*v.w;
            }
            float rv = fmaxf(acc * sc3 + sh3, 0.f);
            m = fmaxf(m, rv);
        }
        s_fm[rg * 128 + c] = m;
        __syncthreads();
        if (rg == 0)
            out_np[(size_t)(8 * bk + gi) * 128 + c] = fmaxf(s_fm[c], s_fm[128 + c]);
        __syncthreads();
    }
}

// ---------------------------------------------------------------- host launch
extern "C" void kernel_launch(void* const* d_in, const int* in_sizes, int n_in,
                              void* d_out, int out_size, void* d_ws, size_t ws_size,
                              hipStream_t stream)
{
    (void)in_sizes; (void)n_in; (void)out_size;
    const float* xyz = (const float*)d_in[0];
    const float* pts = (const float*)d_in[1];
    const float* w1 = (const float*)d_in[2];
    const float* b1 = (const float*)d_in[3];
    const float* g1 = (const float*)d_in[4];
    const float* be1 = (const float*)d_in[5];
    const float* w2 = (const float*)d_in[6];
    const float* b2 = (const float*)d_in[7];
    const float* g2 = (const float*)d_in[8];
    const float* be2 = (const float*)d_in[9];
    const float* w3 = (const float*)d_in[10];
    const float* b3 = (const float*)d_in[11];
    const float* g3 = (const float*)d_in[12];
    const float* be3 = (const float*)d_in[13];

    float* out = (float*)d_out;
    float* newxyz = out;              // 4*1024*3
    float* newpts = out + NB * NS * 3;

    float* y1 = (float*)d_ws;                          // 8388608 f32
    float* y2 = y1 + 8388608;
    float* st = y2 + 8388608;                          // 4096 f32 stat shards
    const size_t needed = (2ull * 8388608ull + 4096ull) * 4ull;
    if (ws_size < needed) return;

    fps_kernel<<<NB + 1, 512, 0, stream>>>(xyz, newxyz, st);
    phaseA_kernel<<<512, 256, 0, stream>>>(xyz, pts, newxyz, w1, b1, y1, st);
    phaseB_kernel<<<512, 256, 0, stream>>>(y1, g1, be1, w2, b2, y2, st);
    phaseC_kernel<<<512, 256, 0, stream>>>(y2, g2, be2, w3, b3, st);
    phaseD_kernel<<<512, 256, 0, stream>>>(y2, g2, be2, g3, be3, w3, b3, st, newpts);
}

// Round 10
// 1394.398 us; speedup vs baseline: 1.0976x; 1.0976x over previous
//
#include <hip/hip_runtime.h>

#define NB 4
#define NP 8192
#define NS 1024
#define NK 32
#define CNT_ALL 131072.0f   // NB*NS*NK
#define NBLK 512            // fused-kernel grid; 2/CU * 256 CU = exactly co-resident

typedef float v2f __attribute__((ext_vector_type(2)));

template <int CTRL>
__device__ __forceinline__ unsigned dpp_max_u32(unsigned m)
{
    unsigned o = (unsigned)__builtin_amdgcn_update_dpp((int)m, (int)m, CTRL, 0xF, 0xF, false);
    return (o > m) ? o : m;
}

template <int CTRL>
__device__ __forceinline__ unsigned long long dpp_max_u64(unsigned long long k)
{
    unsigned lo = (unsigned)k, hi = (unsigned)(k >> 32);
    unsigned olo = (unsigned)__builtin_amdgcn_update_dpp((int)lo, (int)lo, CTRL, 0xF, 0xF, false);
    unsigned ohi = (unsigned)__builtin_amdgcn_update_dpp((int)hi, (int)hi, CTRL, 0xF, 0xF, false);
    unsigned long long o = ((unsigned long long)ohi << 32) | (unsigned long long)olo;
    return (o > k) ? o : k;
}

// ---------------------------------------------------------------- FPS (R3/R7-proven, byte-identical logic)
// Blocks 0..3: FPS per batch. Block 4: zero BN stat shards + barrier counters.
__global__ __launch_bounds__(512, 2) void fps_kernel(const float* __restrict__ xyz,
                                                     float* __restrict__ newxyz,
                                                     float* __restrict__ st)
{
#pragma clang fp contract(off)
    if (blockIdx.x >= NB) {
        for (int i = threadIdx.x; i < 4104; i += 512) st[i] = 0.f;   // stats + 3 ctrs + pad
        return;
    }
    const int b = blockIdx.x;
    const int tid = threadIdx.x;
    const int lane = tid & 63;
    const int w = tid >> 6;                 // 8 waves
    const float* xb = xyz + (size_t)b * NP * 3;

    __shared__ float s_px[NP], s_py[NP], s_pz[NP];      // 96 KB
    __shared__ unsigned long long s_kv[2][8];

#pragma unroll
    for (int k = 0; k < 16; ++k) {
        const int i = k * 512 + tid;
        s_px[i] = xb[3 * i + 0];
        s_py[i] = xb[3 * i + 1];
        s_pz[i] = xb[3 * i + 2];
    }
    __syncthreads();

    v2f px[8], py[8], pz[8], dist[8];
    const int base = tid << 4;
#pragma unroll
    for (int m = 0; m < 8; ++m) {
        const int p0 = base + 2 * m;
        px[m] = v2f{s_px[p0], s_px[p0 + 1]};
        py[m] = v2f{s_py[p0], s_py[p0 + 1]};
        pz[m] = v2f{s_pz[p0], s_pz[p0 + 1]};
        dist[m] = v2f{1e10f, 1e10f};
    }
    float cx = s_px[0], cy = s_py[0], cz = s_pz[0];
    float* ob = newxyz + (size_t)b * NS * 3;

    for (int it = 0; it < NS; ++it) {
        if (tid == 0) { ob[it * 3 + 0] = cx; ob[it * 3 + 1] = cy; ob[it * 3 + 2] = cz; }
        const v2f cxx = v2f{cx, cx}, cyy = v2f{cy, cy}, czz = v2f{cz, cz};
        float bd0 = -1.0f, bd1 = -1.0f;
        int bj0 = 0, bj1 = 0;
#pragma unroll
        for (int m = 0; m < 8; ++m) {
            v2f dx = px[m] - cxx, dy = py[m] - cyy, dz = pz[m] - czz;
            v2f d = (dx * dx + dy * dy) + dz * dz;      // numpy order, no fma
            float d0 = fminf(dist[m].x, d.x);
            float d1 = fminf(dist[m].y, d.y);
            dist[m].x = d0;
            dist[m].y = d1;
            bool t0 = d0 > bd0;
            bd0 = t0 ? d0 : bd0;
            bj0 = t0 ? 2 * m : bj0;
            bool t1 = d1 > bd1;
            bd1 = t1 ? d1 : bd1;
            bj1 = t1 ? 2 * m + 1 : bj1;
        }
        const bool tm = (bd1 > bd0) || ((bd1 == bd0) && (bj1 < bj0));
        const float bd = tm ? bd1 : bd0;
        const int ibest = base + (tm ? bj1 : bj0);
        const unsigned ub = __float_as_uint(bd);
        unsigned m0 = dpp_max_u32<0xB1>(ub);
        m0 = dpp_max_u32<0x4E>(m0);
        m0 = dpp_max_u32<0x141>(m0);
        m0 = dpp_max_u32<0x140>(m0);
        m0 = dpp_max_u32<0x142>(m0);
        m0 = dpp_max_u32<0x143>(m0);
        const unsigned maxbits = (unsigned)__builtin_amdgcn_readlane((int)m0, 63);
        const unsigned long long bm = __ballot(ub == maxbits);
        const int srclane = __ffsll(bm) - 1;
        const int wbi = __builtin_amdgcn_readlane(ibest, srclane);
        if (lane == 0)
            s_kv[it & 1][w] = ((unsigned long long)maxbits << 32) | (unsigned)(NP - 1 - wbi);
        __syncthreads();
        unsigned long long kv = s_kv[it & 1][lane & 7];
        kv = dpp_max_u64<0xB1>(kv);
        kv = dpp_max_u64<0x4E>(kv);
        kv = dpp_max_u64<0x141>(kv);
        const int fi = NP - 1 - (int)(unsigned)(kv & 0xFFFFFFFFull);
        cx = s_px[fi]; cy = s_py[fi]; cz = s_pz[fi];
    }
}

// ---------------------------------------------------------------- device-scope helpers
__device__ __forceinline__ float aload(const float* p)
{
    return __hip_atomic_load((float*)p, __ATOMIC_RELAXED, __HIP_MEMORY_SCOPE_AGENT);
}

// BN scale/shift for channel c from 8-sharded sums (device-coherent reads)
__device__ __forceinline__ void bn_coef_a(const float* __restrict__ sums,
                                          const float* __restrict__ sqs,
                                          const float* __restrict__ g,
                                          const float* __restrict__ be,
                                          int C, int c, float& sc, float& sh)
{
    float s = 0.f, q = 0.f;
#pragma unroll
    for (int k = 0; k < 8; ++k) { s += aload(&sums[k * C + c]); q += aload(&sqs[k * C + c]); }
    const float mean = s / CNT_ALL;
    const float var = q / CNT_ALL - mean * mean;
    sc = g[c] / sqrtf(var + 1e-5f);
    sh = be[c] - mean * sc;
}

// grid barrier: all NBLK blocks co-resident by capacity (LDS 36KB, 256thr -> 2/CU).
__device__ __forceinline__ void gridbar(unsigned* ctr)
{
    __syncthreads();
    if (threadIdx.x == 0) {
        __threadfence();
        __hip_atomic_fetch_add(ctr, 1u, __ATOMIC_RELEASE, __HIP_MEMORY_SCOPE_AGENT);
        while (__hip_atomic_load(ctr, __ATOMIC_ACQUIRE, __HIP_MEMORY_SCOPE_AGENT) < NBLK)
            __builtin_amdgcn_s_sleep(8);
        __threadfence();
    }
    __syncthreads();
}

// ---------------------------------------------------------------- fused A+B+C+D (phase bodies = R7-validated)
// Key invariant: y1/y2 rows [256*bk, 256*bk+256) are produced AND consumed by
// block bk (same CU/L1) -> no cross-block coherence needed for them. Only the
// BN stat shards cross blocks: written with device-scope atomicAdd, read with
// device-scope atomic loads after a gridbar.
__global__ __launch_bounds__(256, 2) void fused_kernel(
    const float* __restrict__ xyz, const float* __restrict__ pts,
    const float* __restrict__ newxyz,
    const float* __restrict__ w1, const float* __restrict__ b1,
    const float* __restrict__ g1, const float* __restrict__ be1,
    const float* __restrict__ w2, const float* __restrict__ b2,
    const float* __restrict__ g2, const float* __restrict__ be2,
    const float* __restrict__ w3, const float* __restrict__ b3,
    const float* __restrict__ g3, const float* __restrict__ be3,
    float* __restrict__ y1, float* __restrict__ y2,
    float* __restrict__ st, float* __restrict__ out_np)
{
    __shared__ __align__(16) char smem[36864];
    const int tid = threadIdx.x;
    const int bk = blockIdx.x;          // 0..511
    const int lane = tid & 63;
    const int wv_id = tid >> 6;

    float* sums1 = st;            float* sqs1 = st + 512;
    float* sums2 = st + 1024;     float* sqs2 = st + 1536;
    float* sums3 = st + 2048;     float* sqs3 = st + 3072;
    unsigned* ctr = (unsigned*)(st + 4096);

    // ---------------- Phase A: ball query + linear1 + stats1
    {
        int*   s_ball = (int*)smem;                       // [8][NK] 1 KB
        float* s_feat = (float*)(smem + 1024);            // [256][20] 20 KB
        float* s_ps   = (float*)(smem + 1024 + 20480);
        float* s_pq   = s_ps + 256;

        const int b = (8 * bk) >> 10;
        const float* xb = xyz + (size_t)b * NP * 3;
        const float rr = (float)(0.2 * 0.2);
        for (int r = 0; r < 2; ++r) {
            const int lg = 2 * wv_id + r;
            const int sg = 8 * bk + lg;
            const float cx = newxyz[sg * 3 + 0];
            const float cy = newxyz[sg * 3 + 1];
            const float cz = newxyz[sg * 3 + 2];
            int cnt = 0;
            for (int base = 0; base < NP && cnt < NK; base += 64) {
                const int p = base + lane;
                float dx = xb[p * 3 + 0] - cx;
                float dy = xb[p * 3 + 1] - cy;
                float dz = xb[p * 3 + 2] - cz;
                float d = __fadd_rn(__fadd_rn(__fmul_rn(dx, dx), __fmul_rn(dy, dy)),
                                    __fmul_rn(dz, dz));
                bool in = (d <= rr);
                unsigned long long mask = __ballot(in);
                int before = __popcll(mask & ((1ull << lane) - 1ull));
                int pos = cnt + before;
                if (in && pos < NK) s_ball[lg * NK + pos] = p;
                cnt += (int)__popcll(mask);
            }
            cnt = min(cnt, NK);
            const int v0 = s_ball[lg * NK];       // cnt >= 1 (centroid itself in-radius)
            if (lane < NK && lane >= cnt) s_ball[lg * NK + lane] = v0;
        }
        __syncthreads();
        {   // stage features: thread t -> row t
            const int lg = tid >> 5, k = tid & 31;
            const int id = s_ball[lg * NK + k];
            const int sg = 8 * bk + lg;
            const float* pp = xyz + ((size_t)b * NP + id) * 3;
            const float* cp = newxyz + (size_t)sg * 3;
            float* f = s_feat + tid * 20;
            f[0] = pp[0] - cp[0];
            f[1] = pp[1] - cp[1];
            f[2] = pp[2] - cp[2];
            const float4* q4 = (const float4*)(pts + ((size_t)b * NP + id) * 16);
#pragma unroll
            for (int i = 0; i < 4; ++i) {
                float4 v = q4[i];
                f[3 + 4 * i + 0] = v.x; f[3 + 4 * i + 1] = v.y;
                f[3 + 4 * i + 2] = v.z; f[3 + 4 * i + 3] = v.w;
            }
            f[19] = 0.f;
        }
        __syncthreads();
        const int c = tid & 63, rg = tid >> 6;
        float wv[20];
#pragma unroll
        for (int j = 0; j < 19; ++j) wv[j] = w1[c * 19 + j];
        wv[19] = 0.f;
        const float bs = b1[c];
        float s = 0.f, q = 0.f;
        for (int r = 0; r < 64; ++r) {
            const int row = rg * 64 + r;
            const float4* f4 = (const float4*)(s_feat + row * 20);
            float acc = bs;
#pragma unroll
            for (int j4 = 0; j4 < 5; ++j4) {
                float4 v = f4[j4];
                acc += wv[4*j4+0]*v.x + wv[4*j4+1]*v.y + wv[4*j4+2]*v.z + wv[4*j4+3]*v.w;
            }
            y1[((size_t)256 * bk + row) * 64 + c] = acc;
            s += acc; q += acc * acc;
        }
        s_ps[tid] = s; s_pq[tid] = q;
        __syncthreads();
        if (rg == 0) {
            float ts = s_ps[c] + s_ps[64 + c] + s_ps[128 + c] + s_ps[192 + c];
            float tq = s_pq[c] + s_pq[64 + c] + s_pq[128 + c] + s_pq[192 + c];
            atomicAdd(&sums1[(bk & 7) * 64 + c], ts);
            atomicAdd(&sqs1[(bk & 7) * 64 + c], tq);
        }
    }
    gridbar(&ctr[0]);

    // ---------------- Phase B: BN1+ReLU + linear2 + stats2
    {
        float* x_lds = (float*)smem;                       // 32 KB
        float* s_sc  = (float*)(smem + 32768);
        float* s_sh  = s_sc + 64;
        float* s_ps  = (float*)(smem + 32768 + 512);
        float* s_pq  = s_ps + 256;
        if (tid < 64) {
            float sc, sh;
            bn_coef_a(sums1, sqs1, g1, be1, 64, tid, sc, sh);
            s_sc[tid] = sc; s_sh[tid] = sh;
        }
        __syncthreads();
        const int c = tid & 63, rg = tid >> 6;
        float wv[64];
#pragma unroll
        for (int j = 0; j < 64; ++j) wv[j] = w2[c * 64 + j];
        const float bs = b2[c];
        float s = 0.f, q = 0.f;
        for (int half = 0; half < 2; ++half) {
            const size_t row0 = (size_t)256 * bk + 128 * half;
            const float4* y1g = (const float4*)(y1 + row0 * 64);
            float4* xl4 = (float4*)x_lds;
#pragma unroll
            for (int i = 0; i < 8; ++i) {
                const int slot = i * 256 + tid;
                float4 v = y1g[slot];
                const int c4 = (slot & 15) * 4;
                float4 o;
                o.x = fmaxf(v.x * s_sc[c4+0] + s_sh[c4+0], 0.f);
                o.y = fmaxf(v.y * s_sc[c4+1] + s_sh[c4+1], 0.f);
                o.z = fmaxf(v.z * s_sc[c4+2] + s_sh[c4+2], 0.f);
                o.w = fmaxf(v.w * s_sc[c4+3] + s_sh[c4+3], 0.f);
                xl4[slot] = o;
            }
            __syncthreads();
            for (int r = 0; r < 32; ++r) {
                const int row = rg * 32 + r;
                const float4* x4 = (const float4*)(x_lds + row * 64);
                float acc = bs;
#pragma unroll
                for (int j4 = 0; j4 < 16; ++j4) {
                    float4 v = x4[j4];
                    acc += wv[4*j4+0]*v.x + wv[4*j4+1]*v.y + wv[4*j4+2]*v.z + wv[4*j4+3]*v.w;
                }
                y2[(row0 + row) * 64 + c] = acc;
                s += acc; q += acc * acc;
            }
            __syncthreads();
        }
        s_ps[tid] = s; s_pq[tid] = q;
        __syncthreads();
        if (rg == 0) {
            float ts = s_ps[c] + s_ps[64 + c] + s_ps[128 + c] + s_ps[192 + c];
            float tq = s_pq[c] + s_pq[64 + c] + s_pq[128 + c] + s_pq[192 + c];
            atomicAdd(&sums2[(bk & 7) * 64 + c], ts);
            atomicAdd(&sqs2[(bk & 7) * 64 + c], tq);
        }
    }
    gridbar(&ctr[1]);

    // ---------------- Phase C: BN2+ReLU + linear3 + stats3
    {
        float* s_x  = (float*)smem;                        // 8 KB
        float* s_sc = (float*)(smem + 32768);
        float* s_sh = s_sc + 64;
        float* s_p3s = (float*)(smem + 32768 + 512);
        float* s_p3q = s_p3s + 256;
        if (tid < 64) {
            float sc, sh;
            bn_coef_a(sums2, sqs2, g2, be2, 64, tid, sc, sh);
            s_sc[tid] = sc; s_sh[tid] = sh;
        }
        __syncthreads();
        const int c = tid & 127, rg = tid >> 7;
        float wv[64];
#pragma unroll
        for (int j = 0; j < 64; ++j) wv[j] = w3[c * 64 + j];
        const float bs = b3[c];
        float s = 0.f, q = 0.f;
        for (int gi = 0; gi < 8; ++gi) {
            const size_t grow0 = (size_t)256 * bk + 32 * gi;
            const float4* y2g = (const float4*)(y2 + grow0 * 64);
            float4* sx4 = (float4*)s_x;
#pragma unroll
            for (int i = 0; i < 2; ++i) {
                const int slot = i * 256 + tid;
                float4 v = y2g[slot];
                const int c4 = (slot & 15) * 4;
                float4 o;
                o.x = fmaxf(v.x * s_sc[c4+0] + s_sh[c4+0], 0.f);
                o.y = fmaxf(v.y * s_sc[c4+1] + s_sh[c4+1], 0.f);
                o.z = fmaxf(v.z * s_sc[c4+2] + s_sh[c4+2], 0.f);
                o.w = fmaxf(v.w * s_sc[c4+3] + s_sh[c4+3], 0.f);
                sx4[slot] = o;
            }
            __syncthreads();
            for (int r = 0; r < 16; ++r) {
                const int row = rg * 16 + r;
                const float4* x4 = (const float4*)(s_x + row * 64);
                float acc = bs;
#pragma unroll
                for (int j4 = 0; j4 < 16; ++j4) {
                    float4 v = x4[j4];
                    acc += wv[4*j4+0]*v.x + wv[4*j4+1]*v.y + wv[4*j4+2]*v.z + wv[4*j4+3]*v.w;
                }
                s += acc; q += acc * acc;
            }
            __syncthreads();
        }
        s_p3s[rg * 128 + c] = s; s_p3q[rg * 128 + c] = q;
        __syncthreads();
        if (rg == 0) {
            atomicAdd(&sums3[(bk & 7) * 128 + c], s_p3s[c] + s_p3s[128 + c]);
            atomicAdd(&sqs3[(bk & 7) * 128 + c], s_p3q[c] + s_p3q[128 + c]);
        }
    }
    gridbar(&ctr[2]);

    // ---------------- Phase D: BN2+ReLU + linear3 + BN3 + ReLU + maxpool
    {
        float* s_x  = (float*)smem;
        float* s_sc = (float*)(smem + 32768);
        float* s_sh = s_sc + 64;
        float* s_fm = (float*)(smem + 32768 + 512);
        if (tid < 64) {
            float sc, sh;
            bn_coef_a(sums2, sqs2, g2, be2, 64, tid, sc, sh);
            s_sc[tid] = sc; s_sh[tid] = sh;
        }
        const int c = tid & 127, rg = tid >> 7;
        float sc3, sh3;
        bn_coef_a(sums3, sqs3, g3, be3, 128, c, sc3, sh3);
        __syncthreads();
        float wv[64];
#pragma unroll
        for (int j = 0; j < 64; ++j) wv[j] = w3[c * 64 + j];
        const float bs = b3[c];
        for (int gi = 0; gi < 8; ++gi) {
            const size_t grow0 = (size_t)256 * bk + 32 * gi;
            const float4* y2g = (const float4*)(y2 + grow0 * 64);
            float4* sx4 = (float4*)s_x;
#pragma unroll
            for (int i = 0; i < 2; ++i) {
                const int slot = i * 256 + tid;
                float4 v = y2g[slot];
                const int c4 = (slot & 15) * 4;
                float4 o;
                o.x = fmaxf(v.x * s_sc[c4+0] + s_sh[c4+0], 0.f);
                o.y = fmaxf(v.y * s_sc[c4+1] + s_sh[c4+1], 0.f);
                o.z = fmaxf(v.z * s_sc[c4+2] + s_sh[c4+2], 0.f);
                o.w = fmaxf(v.w * s_sc[c4+3] + s_sh[c4+3], 0.f);
                sx4[slot] = o;
            }
            __syncthreads();
            float m = 0.f;                       // relu >= 0
            for (int r = 0; r < 16; ++r) {
                const int row = rg * 16 + r;
                const float4* x4 = (const float4*)(s_x + row * 64);
                float acc = bs;
#pragma unroll
                for (int j4 = 0; j4 < 16; ++j4) {
                    float4 v = x4[j4];
                    acc += wv[4*j4+0]*v.x + wv[4*j4+1]*v.y + wv[4*j4+2]*v.z + wv[4*j4+3]*v.w;
                }
                float rv = fmaxf(acc * sc3 + sh3, 0.f);
                m = fmaxf(m, rv);
            }
            s_fm[rg * 128 + c] = m;
            __syncthreads();
            if (rg == 0)
                out_np[(size_t)(8 * bk + gi) * 128 + c] = fmaxf(s_fm[c], s_fm[128 + c]);
            __syncthreads();
        }
    }
}

// ---------------------------------------------------------------- host launch
extern "C" void kernel_launch(void* const* d_in, const int* in_sizes, int n_in,
                              void* d_out, int out_size, void* d_ws, size_t ws_size,
                              hipStream_t stream)
{
    (void)in_sizes; (void)n_in; (void)out_size;
    const float* xyz = (const float*)d_in[0];
    const float* pts = (const float*)d_in[1];
    const float* w1 = (const float*)d_in[2];
    const float* b1 = (const float*)d_in[3];
    const float* g1 = (const float*)d_in[4];
    const float* be1 = (const float*)d_in[5];
    const float* w2 = (const float*)d_in[6];
    const float* b2 = (const float*)d_in[7];
    const float* g2 = (const float*)d_in[8];
    const float* be2 = (const float*)d_in[9];
    const float* w3 = (const float*)d_in[10];
    const float* b3 = (const float*)d_in[11];
    const float* g3 = (const float*)d_in[12];
    const float* be3 = (const float*)d_in[13];

    float* out = (float*)d_out;
    float* newxyz = out;              // 4*1024*3
    float* newpts = out + NB * NS * 3;

    float* y1 = (float*)d_ws;                          // 8388608 f32
    float* y2 = y1 + 8388608;
    float* st = y2 + 8388608;                          // 4096 stats + 3 ctrs + pad
    const size_t needed = (2ull * 8388608ull + 4352ull) * 4ull;
    if (ws_size < needed) return;

    fps_kernel<<<NB + 1, 512, 0, stream>>>(xyz, newxyz, st);
    fused_kernel<<<NBLK, 256, 0, stream>>>(xyz, pts, newxyz,
                                           w1, b1, g1, be1,
                                           w2, b2, g2, be2,
                                           w3, b3, g3, be3,
                                           y1, y2, st, newpts);
}

// Round 11
// 1180.399 us; speedup vs baseline: 1.2966x; 1.1813x over previous
//
#include <hip/hip_runtime.h>

#define NB 4
#define NP 8192
#define NS 1024
#define NK 32
#define CNT_ALL 131072.0f   // NB*NS*NK
#define NBLK 512            // fused-kernel grid; 2/CU * 256 CU = exactly co-resident

typedef float v2f __attribute__((ext_vector_type(2)));

template <int CTRL>
__device__ __forceinline__ unsigned dpp_max_u32(unsigned m)
{
    unsigned o = (unsigned)__builtin_amdgcn_update_dpp((int)m, (int)m, CTRL, 0xF, 0xF, false);
    return (o > m) ? o : m;
}

template <int CTRL>
__device__ __forceinline__ unsigned long long dpp_max_u64(unsigned long long k)
{
    unsigned lo = (unsigned)k, hi = (unsigned)(k >> 32);
    unsigned olo = (unsigned)__builtin_amdgcn_update_dpp((int)lo, (int)lo, CTRL, 0xF, 0xF, false);
    unsigned ohi = (unsigned)__builtin_amdgcn_update_dpp((int)hi, (int)hi, CTRL, 0xF, 0xF, false);
    unsigned long long o = ((unsigned long long)ohi << 32) | (unsigned long long)olo;
    return (o > k) ? o : k;
}

// ---------------------------------------------------------------- FPS (R3/R7-proven, byte-identical logic)
// Blocks 0..3: FPS per batch. Block 4: zero BN stat shards + barrier counters.
__global__ __launch_bounds__(512, 2) void fps_kernel(const float* __restrict__ xyz,
                                                     float* __restrict__ newxyz,
                                                     float* __restrict__ st)
{
#pragma clang fp contract(off)
    if (blockIdx.x >= NB) {
        for (int i = threadIdx.x; i < 4104; i += 512) st[i] = 0.f;   // stats + 3 ctrs + pad
        return;
    }
    const int b = blockIdx.x;
    const int tid = threadIdx.x;
    const int lane = tid & 63;
    const int w = tid >> 6;                 // 8 waves
    const float* xb = xyz + (size_t)b * NP * 3;

    __shared__ float s_px[NP], s_py[NP], s_pz[NP];      // 96 KB
    __shared__ unsigned long long s_kv[2][8];

#pragma unroll
    for (int k = 0; k < 16; ++k) {
        const int i = k * 512 + tid;
        s_px[i] = xb[3 * i + 0];
        s_py[i] = xb[3 * i + 1];
        s_pz[i] = xb[3 * i + 2];
    }
    __syncthreads();

    v2f px[8], py[8], pz[8], dist[8];
    const int base = tid << 4;
#pragma unroll
    for (int m = 0; m < 8; ++m) {
        const int p0 = base + 2 * m;
        px[m] = v2f{s_px[p0], s_px[p0 + 1]};
        py[m] = v2f{s_py[p0], s_py[p0 + 1]};
        pz[m] = v2f{s_pz[p0], s_pz[p0 + 1]};
        dist[m] = v2f{1e10f, 1e10f};
    }
    float cx = s_px[0], cy = s_py[0], cz = s_pz[0];
    float* ob = newxyz + (size_t)b * NS * 3;

    for (int it = 0; it < NS; ++it) {
        if (tid == 0) { ob[it * 3 + 0] = cx; ob[it * 3 + 1] = cy; ob[it * 3 + 2] = cz; }
        const v2f cxx = v2f{cx, cx}, cyy = v2f{cy, cy}, czz = v2f{cz, cz};
        float bd0 = -1.0f, bd1 = -1.0f;
        int bj0 = 0, bj1 = 0;
#pragma unroll
        for (int m = 0; m < 8; ++m) {
            v2f dx = px[m] - cxx, dy = py[m] - cyy, dz = pz[m] - czz;
            v2f d = (dx * dx + dy * dy) + dz * dz;      // numpy order, no fma
            float d0 = fminf(dist[m].x, d.x);
            float d1 = fminf(dist[m].y, d.y);
            dist[m].x = d0;
            dist[m].y = d1;
            bool t0 = d0 > bd0;
            bd0 = t0 ? d0 : bd0;
            bj0 = t0 ? 2 * m : bj0;
            bool t1 = d1 > bd1;
            bd1 = t1 ? d1 : bd1;
            bj1 = t1 ? 2 * m + 1 : bj1;
        }
        const bool tm = (bd1 > bd0) || ((bd1 == bd0) && (bj1 < bj0));
        const float bd = tm ? bd1 : bd0;
        const int ibest = base + (tm ? bj1 : bj0);
        const unsigned ub = __float_as_uint(bd);
        unsigned m0 = dpp_max_u32<0xB1>(ub);
        m0 = dpp_max_u32<0x4E>(m0);
        m0 = dpp_max_u32<0x141>(m0);
        m0 = dpp_max_u32<0x140>(m0);
        m0 = dpp_max_u32<0x142>(m0);
        m0 = dpp_max_u32<0x143>(m0);
        const unsigned maxbits = (unsigned)__builtin_amdgcn_readlane((int)m0, 63);
        const unsigned long long bm = __ballot(ub == maxbits);
        const int srclane = __ffsll(bm) - 1;
        const int wbi = __builtin_amdgcn_readlane(ibest, srclane);
        if (lane == 0)
            s_kv[it & 1][w] = ((unsigned long long)maxbits << 32) | (unsigned)(NP - 1 - wbi);
        __syncthreads();
        unsigned long long kv = s_kv[it & 1][lane & 7];
        kv = dpp_max_u64<0xB1>(kv);
        kv = dpp_max_u64<0x4E>(kv);
        kv = dpp_max_u64<0x141>(kv);
        const int fi = NP - 1 - (int)(unsigned)(kv & 0xFFFFFFFFull);
        cx = s_px[fi]; cy = s_py[fi]; cz = s_pz[fi];
    }
}

// ---------------------------------------------------------------- device-scope helpers
__device__ __forceinline__ float aload(const float* p)
{
    return __hip_atomic_load((float*)p, __ATOMIC_RELAXED, __HIP_MEMORY_SCOPE_AGENT);
}

// BN scale/shift for channel c from 8-sharded sums (coherent relaxed atomic reads)
__device__ __forceinline__ void bn_coef_a(const float* __restrict__ sums,
                                          const float* __restrict__ sqs,
                                          const float* __restrict__ g,
                                          const float* __restrict__ be,
                                          int C, int c, float& sc, float& sh)
{
    float s = 0.f, q = 0.f;
#pragma unroll
    for (int k = 0; k < 8; ++k) { s += aload(&sums[k * C + c]); q += aload(&sqs[k * C + c]); }
    const float mean = s / CNT_ALL;
    const float var = q / CNT_ALL - mean * mean;
    sc = g[c] / sqrtf(var + 1e-5f);
    sh = be[c] - mean * sc;
}

// Fence-free grid barrier (all NBLK blocks co-resident by capacity).
// Correctness: __syncthreads() drains vmcnt for ALL waves (compiler emits
// s_waitcnt vmcnt(0) before s_barrier), so every stat atomicAdd of this block
// has completed at the coherence point before the RELAXED ctr add. Readers
// poll with RELAXED atomic loads (no L1/L2 invalidate traffic - R10's bug was
// ACQUIRE-in-loop + threadfence wbl2) and read stats via relaxed atomic loads,
// which are coherent by construction. y1/y2 are same-block data -> untouched.
__device__ __forceinline__ void gridbar(unsigned* ctr)
{
    __syncthreads();
    if (threadIdx.x == 0) {
        __hip_atomic_fetch_add(ctr, 1u, __ATOMIC_RELAXED, __HIP_MEMORY_SCOPE_AGENT);
        while (__hip_atomic_load(ctr, __ATOMIC_RELAXED, __HIP_MEMORY_SCOPE_AGENT) < NBLK)
            __builtin_amdgcn_s_sleep(2);
    }
    __syncthreads();
}

// ---------------------------------------------------------------- fused A+B+C+D (bodies = R7/R10-validated)
__global__ __launch_bounds__(256, 2) void fused_kernel(
    const float* __restrict__ xyz, const float* __restrict__ pts,
    const float* __restrict__ newxyz,
    const float* __restrict__ w1, const float* __restrict__ b1,
    const float* __restrict__ g1, const float* __restrict__ be1,
    const float* __restrict__ w2, const float* __restrict__ b2,
    const float* __restrict__ g2, const float* __restrict__ be2,
    const float* __restrict__ w3, const float* __restrict__ b3,
    const float* __restrict__ g3, const float* __restrict__ be3,
    float* __restrict__ y1, float* __restrict__ y2,
    float* __restrict__ st, float* __restrict__ out_np)
{
    __shared__ __align__(16) char smem[36864];
    const int tid = threadIdx.x;
    const int bk = blockIdx.x;          // 0..511
    const int lane = tid & 63;
    const int wv_id = tid >> 6;

    float* sums1 = st;            float* sqs1 = st + 512;
    float* sums2 = st + 1024;     float* sqs2 = st + 1536;
    float* sums3 = st + 2048;     float* sqs3 = st + 3072;
    unsigned* ctr = (unsigned*)(st + 4096);

    // ---------------- Phase A: ball query + linear1 + stats1
    {
        int*   s_ball = (int*)smem;                       // [8][NK] 1 KB
        float* s_feat = (float*)(smem + 1024);            // [256][20] 20 KB
        float* s_ps   = (float*)(smem + 1024 + 20480);
        float* s_pq   = s_ps + 256;

        const int b = (8 * bk) >> 10;
        const float* xb = xyz + (size_t)b * NP * 3;
        const float rr = (float)(0.2 * 0.2);
        for (int r = 0; r < 2; ++r) {
            const int lg = 2 * wv_id + r;
            const int sg = 8 * bk + lg;
            const float cx = newxyz[sg * 3 + 0];
            const float cy = newxyz[sg * 3 + 1];
            const float cz = newxyz[sg * 3 + 2];
            int cnt = 0;
            for (int base = 0; base < NP && cnt < NK; base += 64) {
                const int p = base + lane;
                float dx = xb[p * 3 + 0] - cx;
                float dy = xb[p * 3 + 1] - cy;
                float dz = xb[p * 3 + 2] - cz;
                float d = __fadd_rn(__fadd_rn(__fmul_rn(dx, dx), __fmul_rn(dy, dy)),
                                    __fmul_rn(dz, dz));
                bool in = (d <= rr);
                unsigned long long mask = __ballot(in);
                int before = __popcll(mask & ((1ull << lane) - 1ull));
                int pos = cnt + before;
                if (in && pos < NK) s_ball[lg * NK + pos] = p;
                cnt += (int)__popcll(mask);
            }
            cnt = min(cnt, NK);
            const int v0 = s_ball[lg * NK];       // cnt >= 1 (centroid itself in-radius)
            if (lane < NK && lane >= cnt) s_ball[lg * NK + lane] = v0;
        }
        __syncthreads();
        {   // stage features: thread t -> row t
            const int lg = tid >> 5, k = tid & 31;
            const int id = s_ball[lg * NK + k];
            const int sg = 8 * bk + lg;
            const float* pp = xyz + ((size_t)b * NP + id) * 3;
            const float* cp = newxyz + (size_t)sg * 3;
            float* f = s_feat + tid * 20;
            f[0] = pp[0] - cp[0];
            f[1] = pp[1] - cp[1];
            f[2] = pp[2] - cp[2];
            const float4* q4 = (const float4*)(pts + ((size_t)b * NP + id) * 16);
#pragma unroll
            for (int i = 0; i < 4; ++i) {
                float4 v = q4[i];
                f[3 + 4 * i + 0] = v.x; f[3 + 4 * i + 1] = v.y;
                f[3 + 4 * i + 2] = v.z; f[3 + 4 * i + 3] = v.w;
            }
            f[19] = 0.f;
        }
        __syncthreads();
        const int c = tid & 63, rg = tid >> 6;
        float wv[20];
#pragma unroll
        for (int j = 0; j < 19; ++j) wv[j] = w1[c * 19 + j];
        wv[19] = 0.f;
        const float bs = b1[c];
        float s = 0.f, q = 0.f;
        for (int r = 0; r < 64; ++r) {
            const int row = rg * 64 + r;
            const float4* f4 = (const float4*)(s_feat + row * 20);
            float acc = bs;
#pragma unroll
            for (int j4 = 0; j4 < 5; ++j4) {
                float4 v = f4[j4];
                acc += wv[4*j4+0]*v.x + wv[4*j4+1]*v.y + wv[4*j4+2]*v.z + wv[4*j4+3]*v.w;
            }
            y1[((size_t)256 * bk + row) * 64 + c] = acc;
            s += acc; q += acc * acc;
        }
        s_ps[tid] = s; s_pq[tid] = q;
        __syncthreads();
        if (rg == 0) {
            float ts = s_ps[c] + s_ps[64 + c] + s_ps[128 + c] + s_ps[192 + c];
            float tq = s_pq[c] + s_pq[64 + c] + s_pq[128 + c] + s_pq[192 + c];
            atomicAdd(&sums1[(bk & 7) * 64 + c], ts);
            atomicAdd(&sqs1[(bk & 7) * 64 + c], tq);
        }
    }
    gridbar(&ctr[0]);

    // ---------------- Phase B: BN1+ReLU + linear2 + stats2
    {
        float* x_lds = (float*)smem;                       // 32 KB
        float* s_sc  = (float*)(smem + 32768);
        float* s_sh  = s_sc + 64;
        float* s_ps  = (float*)(smem + 32768 + 512);
        float* s_pq  = s_ps + 256;
        if (tid < 64) {
            float sc, sh;
            bn_coef_a(sums1, sqs1, g1, be1, 64, tid, sc, sh);
            s_sc[tid] = sc; s_sh[tid] = sh;
        }
        __syncthreads();
        const int c = tid & 63, rg = tid >> 6;
        float wv[64];
#pragma unroll
        for (int j = 0; j < 64; ++j) wv[j] = w2[c * 64 + j];
        const float bs = b2[c];
        float s = 0.f, q = 0.f;
        for (int half = 0; half < 2; ++half) {
            const size_t row0 = (size_t)256 * bk + 128 * half;
            const float4* y1g = (const float4*)(y1 + row0 * 64);
            float4* xl4 = (float4*)x_lds;
#pragma unroll
            for (int i = 0; i < 8; ++i) {
                const int slot = i * 256 + tid;
                float4 v = y1g[slot];
                const int c4 = (slot & 15) * 4;
                float4 o;
                o.x = fmaxf(v.x * s_sc[c4+0] + s_sh[c4+0], 0.f);
                o.y = fmaxf(v.y * s_sc[c4+1] + s_sh[c4+1], 0.f);
                o.z = fmaxf(v.z * s_sc[c4+2] + s_sh[c4+2], 0.f);
                o.w = fmaxf(v.w * s_sc[c4+3] + s_sh[c4+3], 0.f);
                xl4[slot] = o;
            }
            __syncthreads();
            for (int r = 0; r < 32; ++r) {
                const int row = rg * 32 + r;
                const float4* x4 = (const float4*)(x_lds + row * 64);
                float acc = bs;
#pragma unroll
                for (int j4 = 0; j4 < 16; ++j4) {
                    float4 v = x4[j4];
                    acc += wv[4*j4+0]*v.x + wv[4*j4+1]*v.y + wv[4*j4+2]*v.z + wv[4*j4+3]*v.w;
                }
                y2[(row0 + row) * 64 + c] = acc;
                s += acc; q += acc * acc;
            }
            __syncthreads();
        }
        s_ps[tid] = s; s_pq[tid] = q;
        __syncthreads();
        if (rg == 0) {
            float ts = s_ps[c] + s_ps[64 + c] + s_ps[128 + c] + s_ps[192 + c];
            float tq = s_pq[c] + s_pq[64 + c] + s_pq[128 + c] + s_pq[192 + c];
            atomicAdd(&sums2[(bk & 7) * 64 + c], ts);
            atomicAdd(&sqs2[(bk & 7) * 64 + c], tq);
        }
    }
    gridbar(&ctr[1]);

    // ---------------- Phase C: BN2+ReLU + linear3 + stats3
    {
        float* s_x  = (float*)smem;                        // 8 KB
        float* s_sc = (float*)(smem + 32768);
        float* s_sh = s_sc + 64;
        float* s_p3s = (float*)(smem + 32768 + 512);
        float* s_p3q = s_p3s + 256;
        if (tid < 64) {
            float sc, sh;
            bn_coef_a(sums2, sqs2, g2, be2, 64, tid, sc, sh);
            s_sc[tid] = sc; s_sh[tid] = sh;
        }
        __syncthreads();
        const int c = tid & 127, rg = tid >> 7;
        float wv[64];
#pragma unroll
        for (int j = 0; j < 64; ++j) wv[j] = w3[c * 64 + j];
        const float bs = b3[c];
        float s = 0.f, q = 0.f;
        for (int gi = 0; gi < 8; ++gi) {
            const size_t grow0 = (size_t)256 * bk + 32 * gi;
            const float4* y2g = (const float4*)(y2 + grow0 * 64);
            float4* sx4 = (float4*)s_x;
#pragma unroll
            for (int i = 0; i < 2; ++i) {
                const int slot = i * 256 + tid;
                float4 v = y2g[slot];
                const int c4 = (slot & 15) * 4;
                float4 o;
                o.x = fmaxf(v.x * s_sc[c4+0] + s_sh[c4+0], 0.f);
                o.y = fmaxf(v.y * s_sc[c4+1] + s_sh[c4+1], 0.f);
                o.z = fmaxf(v.z * s_sc[c4+2] + s_sh[c4+2], 0.f);
                o.w = fmaxf(v.w * s_sc[c4+3] + s_sh[c4+3], 0.f);
                sx4[slot] = o;
            }
            __syncthreads();
            for (int r = 0; r < 16; ++r) {
                const int row = rg * 16 + r;
                const float4* x4 = (const float4*)(s_x + row * 64);
                float acc = bs;
#pragma unroll
                for (int j4 = 0; j4 < 16; ++j4) {
                    float4 v = x4[j4];
                    acc += wv[4*j4+0]*v.x + wv[4*j4+1]*v.y + wv[4*j4+2]*v.z + wv[4*j4+3]*v.w;
                }
                s += acc; q += acc * acc;
            }
            __syncthreads();
        }
        s_p3s[rg * 128 + c] = s; s_p3q[rg * 128 + c] = q;
        __syncthreads();
        if (rg == 0) {
            atomicAdd(&sums3[(bk & 7) * 128 + c], s_p3s[c] + s_p3s[128 + c]);
            atomicAdd(&sqs3[(bk & 7) * 128 + c], s_p3q[c] + s_p3q[128 + c]);
        }
    }
    gridbar(&ctr[2]);

    // ---------------- Phase D: BN2+ReLU + linear3 + BN3 + ReLU + maxpool
    {
        float* s_x  = (float*)smem;
        float* s_sc = (float*)(smem + 32768);
        float* s_sh = s_sc + 64;
        float* s_fm = (float*)(smem + 32768 + 512);
        if (tid < 64) {
            float sc, sh;
            bn_coef_a(sums2, sqs2, g2, be2, 64, tid, sc, sh);
            s_sc[tid] = sc; s_sh[tid] = sh;
        }
        const int c = tid & 127, rg = tid >> 7;
        float sc3, sh3;
        bn_coef_a(sums3, sqs3, g3, be3, 128, c, sc3, sh3);
        __syncthreads();
        float wv[64];
#pragma unroll
        for (int j = 0; j < 64; ++j) wv[j] = w3[c * 64 + j];
        const float bs = b3[c];
        for (int gi = 0; gi < 8; ++gi) {
            const size_t grow0 = (size_t)256 * bk + 32 * gi;
            const float4* y2g = (const float4*)(y2 + grow0 * 64);
            float4* sx4 = (float4*)s_x;
#pragma unroll
            for (int i = 0; i < 2; ++i) {
                const int slot = i * 256 + tid;
                float4 v = y2g[slot];
                const int c4 = (slot & 15) * 4;
                float4 o;
                o.x = fmaxf(v.x * s_sc[c4+0] + s_sh[c4+0], 0.f);
                o.y = fmaxf(v.y * s_sc[c4+1] + s_sh[c4+1], 0.f);
                o.z = fmaxf(v.z * s_sc[c4+2] + s_sh[c4+2], 0.f);
                o.w = fmaxf(v.w * s_sc[c4+3] + s_sh[c4+3], 0.f);
                sx4[slot] = o;
            }
            __syncthreads();
            float m = 0.f;                       // relu >= 0
            for (int r = 0; r < 16; ++r) {
                const int row = rg * 16 + r;
                const float4* x4 = (const float4*)(s_x + row * 64);
                float acc = bs;
#pragma unroll
                for (int j4 = 0; j4 < 16; ++j4) {
                    float4 v = x4[j4];
                    acc += wv[4*j4+0]*v.x + wv[4*j4+1]*v.y + wv[4*j4+2]*v.z + wv[4*j4+3]*v.w;
                }
                float rv = fmaxf(acc * sc3 + sh3, 0.f);
                m = fmaxf(m, rv);
            }
            s_fm[rg * 128 + c] = m;
            __syncthreads();
            if (rg == 0)
                out_np[(size_t)(8 * bk + gi) * 128 + c] = fmaxf(s_fm[c], s_fm[128 + c]);
            __syncthreads();
        }
    }
}

// ---------------------------------------------------------------- host launch
extern "C" void kernel_launch(void* const* d_in, const int* in_sizes, int n_in,
                              void* d_out, int out_size, void* d_ws, size_t ws_size,
                              hipStream_t stream)
{
    (void)in_sizes; (void)n_in; (void)out_size;
    const float* xyz = (const float*)d_in[0];
    const float* pts = (const float*)d_in[1];
    const float* w1 = (const float*)d_in[2];
    const float* b1 = (const float*)d_in[3];
    const float* g1 = (const float*)d_in[4];
    const float* be1 = (const float*)d_in[5];
    const float* w2 = (const float*)d_in[6];
    const float* b2 = (const float*)d_in[7];
    const float* g2 = (const float*)d_in[8];
    const float* be2 = (const float*)d_in[9];
    const float* w3 = (const float*)d_in[10];
    const float* b3 = (const float*)d_in[11];
    const float* g3 = (const float*)d_in[12];
    const float* be3 = (const float*)d_in[13];

    float* out = (float*)d_out;
    float* newxyz = out;              // 4*1024*3
    float* newpts = out + NB * NS * 3;

    float* y1 = (float*)d_ws;                          // 8388608 f32
    float* y2 = y1 + 8388608;
    float* st = y2 + 8388608;                          // 4096 stats + 3 ctrs + pad
    const size_t needed = (2ull * 8388608ull + 4352ull) * 4ull;
    if (ws_size < needed) return;

    fps_kernel<<<NB + 1, 512, 0, stream>>>(xyz, newxyz, st);
    fused_kernel<<<NBLK, 256, 0, stream>>>(xyz, pts, newxyz,
                                           w1, b1, g1, be1,
                                           w2, b2, g2, be2,
                                           w3, b3, g3, be3,
                                           y1, y2, st, newpts);
}

// Round 12
// 1078.541 us; speedup vs baseline: 1.4191x; 1.0944x over previous
//
#include <hip/hip_runtime.h>

#define NB 4
#define NP 8192
#define NS 1024
#define NK 32
#define CNT_ALL 131072.0f   // NB*NS*NK

typedef float v2f __attribute__((ext_vector_type(2)));
typedef unsigned long long u64;

#define AGENT __HIP_MEMORY_SCOPE_AGENT

template <int CTRL>
__device__ __forceinline__ unsigned dpp_max_u32(unsigned m)
{
    unsigned o = (unsigned)__builtin_amdgcn_update_dpp((int)m, (int)m, CTRL, 0xF, 0xF, false);
    return (o > m) ? o : m;
}

template <int CTRL>
__device__ __forceinline__ u64 dpp_max_u64(u64 k)
{
    unsigned lo = (unsigned)k, hi = (unsigned)(k >> 32);
    unsigned olo = (unsigned)__builtin_amdgcn_update_dpp((int)lo, (int)lo, CTRL, 0xF, 0xF, false);
    unsigned ohi = (unsigned)__builtin_amdgcn_update_dpp((int)hi, (int)hi, CTRL, 0xF, 0xF, false);
    u64 o = ((u64)ohi << 32) | (u64)olo;
    return (o > k) ? o : k;
}

// ---------------------------------------------------------------- K1: fps (blocks 0..3) || phase A (blocks 4..131)
// fps publishes centroids incrementally: at iter `it` thread0 stores prog=it
// (RELAXED agent) meaning centroids 0..it-1 are globally visible. Safe because
// centroid it-1's atomic stores were drained by the compiler's
// s_waitcnt vmcnt(0) before the iter-(it-1) __syncthreads barrier, which
// precedes the prog=it issue in thread0's program order. No fences in the loop.
// A-blocks (128 x 512thr, 32 groups each in 4 chunks) spin on prog with
// relaxed agent loads + s_sleep, then run ballquery+linear1+stats1. Capacity
// proof: 132 blocks <= 256 CUs, each fits alone -> all resident, no deadlock.
__global__ __launch_bounds__(512, 1) void k1_kernel(
    const float* __restrict__ xyz, const float* __restrict__ pts,
    float* __restrict__ newxyz,
    const float* __restrict__ w1, const float* __restrict__ b1,
    float* __restrict__ y1, float* __restrict__ st, unsigned* __restrict__ prog)
{
    __shared__ __align__(16) char smem[98432];
    const int tid = threadIdx.x;
    const int lane = tid & 63;
    const int wv = tid >> 6;                    // 8 waves

    if (blockIdx.x < NB) {
        // ======================= FPS path (R3/R7-proven math) =======================
#pragma clang fp contract(off)
        float* s_px = (float*)smem;
        float* s_py = (float*)(smem + 32768);
        float* s_pz = (float*)(smem + 65536);
        u64*   s_kv = (u64*)(smem + 98304);     // [2][8]
        const int b = blockIdx.x;
        const float* xb = xyz + (size_t)b * NP * 3;

#pragma unroll
        for (int k = 0; k < 16; ++k) {
            const int i = k * 512 + tid;
            s_px[i] = xb[3 * i + 0];
            s_py[i] = xb[3 * i + 1];
            s_pz[i] = xb[3 * i + 2];
        }
        __syncthreads();

        v2f px[8], py[8], pz[8], dist[8];
        const int base = tid << 4;
#pragma unroll
        for (int m = 0; m < 8; ++m) {
            const int p0 = base + 2 * m;
            px[m] = v2f{s_px[p0], s_px[p0 + 1]};
            py[m] = v2f{s_py[p0], s_py[p0 + 1]};
            pz[m] = v2f{s_pz[p0], s_pz[p0 + 1]};
            dist[m] = v2f{1e10f, 1e10f};
        }
        float cx = s_px[0], cy = s_py[0], cz = s_pz[0];
        float* ob = newxyz + (size_t)b * NS * 3;

        for (int it = 0; it < NS; ++it) {
            if (tid == 0) {
                __hip_atomic_store(&prog[b], (unsigned)it, __ATOMIC_RELAXED, AGENT);
                __hip_atomic_store(&ob[it * 3 + 0], cx, __ATOMIC_RELAXED, AGENT);
                __hip_atomic_store(&ob[it * 3 + 1], cy, __ATOMIC_RELAXED, AGENT);
                __hip_atomic_store(&ob[it * 3 + 2], cz, __ATOMIC_RELAXED, AGENT);
            }
            const v2f cxx = v2f{cx, cx}, cyy = v2f{cy, cy}, czz = v2f{cz, cz};
            float bd0 = -1.0f, bd1 = -1.0f;
            int bj0 = 0, bj1 = 0;
#pragma unroll
            for (int m = 0; m < 8; ++m) {
                v2f dx = px[m] - cxx, dy = py[m] - cyy, dz = pz[m] - czz;
                v2f d = (dx * dx + dy * dy) + dz * dz;      // numpy order, no fma
                float d0 = fminf(dist[m].x, d.x);
                float d1 = fminf(dist[m].y, d.y);
                dist[m].x = d0;
                dist[m].y = d1;
                bool t0 = d0 > bd0;
                bd0 = t0 ? d0 : bd0;
                bj0 = t0 ? 2 * m : bj0;
                bool t1 = d1 > bd1;
                bd1 = t1 ? d1 : bd1;
                bj1 = t1 ? 2 * m + 1 : bj1;
            }
            const bool tm = (bd1 > bd0) || ((bd1 == bd0) && (bj1 < bj0));
            const float bd = tm ? bd1 : bd0;
            const int ibest = base + (tm ? bj1 : bj0);
            const unsigned ub = __float_as_uint(bd);
            unsigned m0 = dpp_max_u32<0xB1>(ub);
            m0 = dpp_max_u32<0x4E>(m0);
            m0 = dpp_max_u32<0x141>(m0);
            m0 = dpp_max_u32<0x140>(m0);
            m0 = dpp_max_u32<0x142>(m0);
            m0 = dpp_max_u32<0x143>(m0);
            const unsigned maxbits = (unsigned)__builtin_amdgcn_readlane((int)m0, 63);
            const u64 bm = __ballot(ub == maxbits);
            const int srclane = __ffsll(bm) - 1;
            const int wbi = __builtin_amdgcn_readlane(ibest, srclane);
            if (lane == 0)
                s_kv[(it & 1) * 8 + wv] = ((u64)maxbits << 32) | (unsigned)(NP - 1 - wbi);
            __syncthreads();                      // drains centroid stores too
            u64 kv = s_kv[(it & 1) * 8 + (lane & 7)];
            kv = dpp_max_u64<0xB1>(kv);
            kv = dpp_max_u64<0x4E>(kv);
            kv = dpp_max_u64<0x141>(kv);
            const int fi = NP - 1 - (int)(unsigned)(kv & 0xFFFFFFFFull);
            cx = s_px[fi]; cy = s_py[fi]; cz = s_pz[fi];
        }
        if (tid == 0)
            __hip_atomic_store(&prog[b], (unsigned)NS, __ATOMIC_RELAXED, AGENT);
        return;
    }

    // ======================= Phase A path =======================
    int*   s_ball = (int*)smem;                    // [8][NK]
    float* s_cent = (float*)(smem + 1024);         // [8][4]
    float* s_feat = (float*)(smem + 1152);         // [256][20]
    float* s_ps   = (float*)(smem + 1152 + 20480); // [512]
    float* s_pq   = s_ps + 512;

    const int abk = blockIdx.x - NB;               // 0..127
    const int b = abk >> 5;                        // 32 blocks/batch
    const int s0 = (abk & 31) * 32;                // local centroid base
    const float* xb = xyz + (size_t)b * NP * 3;
    const float rr = (float)(0.2 * 0.2);

    const int c = tid & 63, rg = tid >> 6;
    float wvr[20];
#pragma unroll
    for (int j = 0; j < 19; ++j) wvr[j] = w1[c * 19 + j];
    wvr[19] = 0.f;
    const float bs = b1[c];
    float sa = 0.f, qa = 0.f;

    for (int chunk = 0; chunk < 4; ++chunk) {
        const int sl = s0 + chunk * 8;             // local centroid index of group 0
        if (tid == 0) {
            while ((int)__hip_atomic_load(&prog[b], __ATOMIC_RELAXED, AGENT) < sl + 8)
                __builtin_amdgcn_s_sleep(4);
        }
        __syncthreads();                            // wait done; s_ball/s_feat reusable
        // ---- ball query: wave wv -> group sl+wv
        {
            const int sg = (b << 10) + sl + wv;     // global group
            float cxv, cyv, czv;
            if (lane == 0) {
                cxv = __hip_atomic_load(&newxyz[sg * 3 + 0], __ATOMIC_RELAXED, AGENT);
                cyv = __hip_atomic_load(&newxyz[sg * 3 + 1], __ATOMIC_RELAXED, AGENT);
                czv = __hip_atomic_load(&newxyz[sg * 3 + 2], __ATOMIC_RELAXED, AGENT);
                s_cent[wv * 4 + 0] = cxv;
                s_cent[wv * 4 + 1] = cyv;
                s_cent[wv * 4 + 2] = czv;
            }
            cxv = __shfl(cxv, 0); cyv = __shfl(cyv, 0); czv = __shfl(czv, 0);
            int cnt = 0;
            for (int bse = 0; bse < NP && cnt < NK; bse += 64) {
                const int p = bse + lane;
                float dx = xb[p * 3 + 0] - cxv;
                float dy = xb[p * 3 + 1] - cyv;
                float dz = xb[p * 3 + 2] - czv;
                float d = __fadd_rn(__fadd_rn(__fmul_rn(dx, dx), __fmul_rn(dy, dy)),
                                    __fmul_rn(dz, dz));
                bool in = (d <= rr);
                u64 mask = __ballot(in);
                int before = __popcll(mask & ((1ull << lane) - 1ull));
                int pos = cnt + before;
                if (in && pos < NK) s_ball[wv * NK + pos] = p;
                cnt += (int)__popcll(mask);
            }
            cnt = min(cnt, NK);
            const int v0 = s_ball[wv * NK];         // cnt >= 1 (centroid in-radius)
            if (lane < NK && lane >= cnt) s_ball[wv * NK + lane] = v0;
        }
        __syncthreads();
        // ---- stage features (threads 0..255 -> rows 0..255)
        if (tid < 256) {
            const int lg = tid >> 5, k = tid & 31;
            const int id = s_ball[lg * NK + k];
            const float* pp = xyz + ((size_t)b * NP + id) * 3;
            float* f = s_feat + tid * 20;
            f[0] = pp[0] - s_cent[lg * 4 + 0];
            f[1] = pp[1] - s_cent[lg * 4 + 1];
            f[2] = pp[2] - s_cent[lg * 4 + 2];
            const float4* q4 = (const float4*)(pts + ((size_t)b * NP + id) * 16);
#pragma unroll
            for (int i = 0; i < 4; ++i) {
                float4 v = q4[i];
                f[3 + 4 * i + 0] = v.x; f[3 + 4 * i + 1] = v.y;
                f[3 + 4 * i + 2] = v.z; f[3 + 4 * i + 3] = v.w;
            }
            f[19] = 0.f;
        }
        __syncthreads();
        // ---- GEMV: thread owns channel c, rows rg*32..+31 of the 256 chunk rows
        const size_t rowbase = (size_t)abk * 1024 + (size_t)chunk * 256;
        for (int r = 0; r < 32; ++r) {
            const int row = rg * 32 + r;
            const float4* f4 = (const float4*)(s_feat + row * 20);
            float acc = bs;
#pragma unroll
            for (int j4 = 0; j4 < 5; ++j4) {
                float4 v = f4[j4];
                acc += wvr[4*j4+0]*v.x + wvr[4*j4+1]*v.y + wvr[4*j4+2]*v.z + wvr[4*j4+3]*v.w;
            }
            y1[(rowbase + row) * 64 + c] = acc;
            sa += acc; qa += acc * acc;
        }
        __syncthreads();                            // protect s_feat/s_ball for next chunk
    }
    s_ps[tid] = sa; s_pq[tid] = qa;
    __syncthreads();
    if (tid < 64) {
        float ts = 0.f, tq = 0.f;
#pragma unroll
        for (int i = 0; i < 8; ++i) { ts += s_ps[i * 64 + tid]; tq += s_pq[i * 64 + tid]; }
        atomicAdd(&st[(abk & 7) * 64 + tid], ts);          // sums1 shard
        atomicAdd(&st[512 + (abk & 7) * 64 + tid], tq);    // sqs1 shard
    }
}

// BN scale/shift for channel c from 8-sharded sums (cross-dispatch, plain loads)
__device__ __forceinline__ void bn_coef(const float* __restrict__ sums,
                                        const float* __restrict__ sqs,
                                        const float* __restrict__ g,
                                        const float* __restrict__ be,
                                        int C, int c, float& sc, float& sh)
{
    float s = 0.f, q = 0.f;
#pragma unroll
    for (int k = 0; k < 8; ++k) { s += sums[k * C + c]; q += sqs[k * C + c]; }
    const float mean = s / CNT_ALL;
    const float var = q / CNT_ALL - mean * mean;
    sc = g[c] / sqrtf(var + 1e-5f);
    sh = be[c] - mean * sc;
}

// ---------------------------------------------------------------- Phase B: BN1+ReLU + linear2 + stats2 (R7-validated)
__global__ __launch_bounds__(256) void phaseB_kernel(
    const float* __restrict__ y1,
    const float* __restrict__ g1, const float* __restrict__ be1,
    const float* __restrict__ w2, const float* __restrict__ b2,
    float* __restrict__ y2, float* __restrict__ st)
{
    __shared__ float x_lds[128 * 64];       // 32 KB
    __shared__ float s_sc[64], s_sh[64];
    __shared__ float s_ps[256], s_pq[256];
    const float* sums1 = st;
    const float* sqs1 = st + 512;
    float* sums2 = st + 1024;
    float* sqs2 = st + 1536;

    const int tid = threadIdx.x;
    const int bk = blockIdx.x;
    if (tid < 64) {
        float sc, sh;
        bn_coef(sums1, sqs1, g1, be1, 64, tid, sc, sh);
        s_sc[tid] = sc; s_sh[tid] = sh;
    }
    __syncthreads();
    const int c = tid & 63, rg = tid >> 6;
    float wv[64];
#pragma unroll
    for (int j = 0; j < 64; ++j) wv[j] = w2[c * 64 + j];
    const float bs = b2[c];
    float s = 0.f, q = 0.f;
    for (int half = 0; half < 2; ++half) {
        const size_t row0 = (size_t)256 * bk + 128 * half;
        const float4* y1g = (const float4*)(y1 + row0 * 64);
        float4* xl4 = (float4*)x_lds;
#pragma unroll
        for (int i = 0; i < 8; ++i) {
            const int slot = i * 256 + tid;
            float4 v = y1g[slot];
            const int c4 = (slot & 15) * 4;
            float4 o;
            o.x = fmaxf(v.x * s_sc[c4+0] + s_sh[c4+0], 0.f);
            o.y = fmaxf(v.y * s_sc[c4+1] + s_sh[c4+1], 0.f);
            o.z = fmaxf(v.z * s_sc[c4+2] + s_sh[c4+2], 0.f);
            o.w = fmaxf(v.w * s_sc[c4+3] + s_sh[c4+3], 0.f);
            xl4[slot] = o;
        }
        __syncthreads();
        for (int r = 0; r < 32; ++r) {
            const int row = rg * 32 + r;
            const float4* x4 = (const float4*)(x_lds + row * 64);
            float acc = bs;
#pragma unroll
            for (int j4 = 0; j4 < 16; ++j4) {
                float4 v = x4[j4];
                acc += wv[4*j4+0]*v.x + wv[4*j4+1]*v.y + wv[4*j4+2]*v.z + wv[4*j4+3]*v.w;
            }
            y2[(row0 + row) * 64 + c] = acc;
            s += acc; q += acc * acc;
        }
        __syncthreads();
    }
    s_ps[tid] = s; s_pq[tid] = q;
    __syncthreads();
    if (rg == 0) {
        float ts = s_ps[c] + s_ps[64 + c] + s_ps[128 + c] + s_ps[192 + c];
        float tq = s_pq[c] + s_pq[64 + c] + s_pq[128 + c] + s_pq[192 + c];
        atomicAdd(&sums2[(bk & 7) * 64 + c], ts);
        atomicAdd(&sqs2[(bk & 7) * 64 + c], tq);
    }
}

// ---------------------------------------------------------------- Phase C': BN2+ReLU + linear3 + stats3 + per-(g,c) max/min
__global__ __launch_bounds__(256) void phaseC2_kernel(
    const float* __restrict__ y2,
    const float* __restrict__ g2, const float* __restrict__ be2,
    const float* __restrict__ w3, const float* __restrict__ b3,
    float* __restrict__ st, float* __restrict__ mxb, float* __restrict__ mnb)
{
    __shared__ float s_x[NK * 64];          // 8 KB
    __shared__ float s_sc[64], s_sh[64];
    __shared__ float s_p3s[256], s_p3q[256];
    __shared__ float s_mx[256], s_mn[256];
    const float* sums2 = st + 1024;
    const float* sqs2 = st + 1536;
    float* sums3 = st + 2048;
    float* sqs3 = st + 3072;

    const int tid = threadIdx.x;
    const int bk = blockIdx.x;              // 512 blocks x 8 groups
    if (tid < 64) {
        float sc, sh;
        bn_coef(sums2, sqs2, g2, be2, 64, tid, sc, sh);
        s_sc[tid] = sc; s_sh[tid] = sh;
    }
    __syncthreads();
    const int c = tid & 127, rg = tid >> 7;
    float wv[64];
#pragma unroll
    for (int j = 0; j < 64; ++j) wv[j] = w3[c * 64 + j];
    const float bs = b3[c];
    float s = 0.f, q = 0.f;
    for (int gi = 0; gi < 8; ++gi) {
        const size_t grow0 = (size_t)256 * bk + 32 * gi;
        const float4* y2g = (const float4*)(y2 + grow0 * 64);
        float4* sx4 = (float4*)s_x;
#pragma unroll
        for (int i = 0; i < 2; ++i) {
            const int slot = i * 256 + tid;
            float4 v = y2g[slot];
            const int c4 = (slot & 15) * 4;
            float4 o;
            o.x = fmaxf(v.x * s_sc[c4+0] + s_sh[c4+0], 0.f);
            o.y = fmaxf(v.y * s_sc[c4+1] + s_sh[c4+1], 0.f);
            o.z = fmaxf(v.z * s_sc[c4+2] + s_sh[c4+2], 0.f);
            o.w = fmaxf(v.w * s_sc[c4+3] + s_sh[c4+3], 0.f);
            sx4[slot] = o;
        }
        __syncthreads();
        float mx = -1e30f, mn = 1e30f;
        for (int r = 0; r < 16; ++r) {
            const int row = rg * 16 + r;
            const float4* x4 = (const float4*)(s_x + row * 64);
            float acc = bs;
#pragma unroll
            for (int j4 = 0; j4 < 16; ++j4) {
                float4 v = x4[j4];
                acc += wv[4*j4+0]*v.x + wv[4*j4+1]*v.y + wv[4*j4+2]*v.z + wv[4*j4+3]*v.w;
            }
            s += acc; q += acc * acc;
            mx = fmaxf(mx, acc); mn = fminf(mn, acc);
        }
        s_mx[rg * 128 + c] = mx; s_mn[rg * 128 + c] = mn;
        __syncthreads();
        if (rg == 0) {
            const size_t gidx = (size_t)(8 * bk + gi) * 128 + c;
            mxb[gidx] = fmaxf(s_mx[c], s_mx[128 + c]);
            mnb[gidx] = fminf(s_mn[c], s_mn[128 + c]);
        }
        __syncthreads();
    }
    s_p3s[rg * 128 + c] = s; s_p3q[rg * 128 + c] = q;
    __syncthreads();
    if (rg == 0) {
        atomicAdd(&sums3[(bk & 7) * 128 + c], s_p3s[c] + s_p3s[128 + c]);
        atomicAdd(&sqs3[(bk & 7) * 128 + c], s_p3q[c] + s_p3q[128 + c]);
    }
}

// ---------------------------------------------------------------- Phase D': BN3+ReLU+maxpool via monotonicity (bit-exact)
__global__ __launch_bounds__(256) void phaseD2_kernel(
    const float* __restrict__ st,
    const float* __restrict__ g3, const float* __restrict__ be3,
    const float* __restrict__ mxb, const float* __restrict__ mnb,
    float* __restrict__ out_np)
{
    const int idx = blockIdx.x * 256 + threadIdx.x;   // < 524288
    const int c = idx & 127;
    float sc, sh;
    bn_coef(st + 2048, st + 3072, g3, be3, 128, c, sc, sh);
    const float sel = (sc >= 0.f) ? mxb[idx] : mnb[idx];
    out_np[idx] = fmaxf(sel * sc + sh, 0.f);
}

// ---------------------------------------------------------------- host launch
extern "C" void kernel_launch(void* const* d_in, const int* in_sizes, int n_in,
                              void* d_out, int out_size, void* d_ws, size_t ws_size,
                              hipStream_t stream)
{
    (void)in_sizes; (void)n_in; (void)out_size;
    const float* xyz = (const float*)d_in[0];
    const float* pts = (const float*)d_in[1];
    const float* w1 = (const float*)d_in[2];
    const float* b1 = (const float*)d_in[3];
    const float* g1 = (const float*)d_in[4];
    const float* be1 = (const float*)d_in[5];
    const float* w2 = (const float*)d_in[6];
    const float* b2 = (const float*)d_in[7];
    const float* g2 = (const float*)d_in[8];
    const float* be2 = (const float*)d_in[9];
    const float* w3 = (const float*)d_in[10];
    const float* b3 = (const float*)d_in[11];
    const float* g3 = (const float*)d_in[12];
    const float* be3 = (const float*)d_in[13];

    float* out = (float*)d_out;
    float* newxyz = out;              // 4*1024*3
    float* newpts = out + NB * NS * 3;

    float* y1 = (float*)d_ws;                          // 8388608 f32
    float* y2 = y1 + 8388608;
    float* st = y2 + 8388608;                          // 4096 stats
    unsigned* prog = (unsigned*)(st + 4096);           // 4 progress ctrs
    float* mxb = st + 4104;                            // 524288
    float* mnb = mxb + 524288;
    const size_t needed = (2ull * 8388608ull + 4104ull + 2ull * 524288ull) * 4ull;
    if (ws_size < needed) return;

    hipMemsetAsync(st, 0, (4096 + 8) * sizeof(float), stream);   // stats + prog
    k1_kernel<<<NB + 128, 512, 0, stream>>>(xyz, pts, newxyz, w1, b1, y1, st, prog);
    phaseB_kernel<<<512, 256, 0, stream>>>(y1, g1, be1, w2, b2, y2, st);
    phaseC2_kernel<<<512, 256, 0, stream>>>(y2, g2, be2, w3, b3, st, mxb, mnb);
    phaseD2_kernel<<<2048, 256, 0, stream>>>(st, g3, be3, mxb, mnb, newpts);
}

// Round 13
// 1002.539 us; speedup vs baseline: 1.5266x; 1.0758x over previous
//
#include <hip/hip_runtime.h>

#define NB 4
#define NP 8192
#define NS 1024
#define NK 32
#define CNT_ALL 131072.0f   // NB*NS*NK

typedef float v2f __attribute__((ext_vector_type(2)));
typedef unsigned long long u64;

#define AGENT __HIP_MEMORY_SCOPE_AGENT

template <int CTRL>
__device__ __forceinline__ unsigned dpp_max_u32(unsigned m)
{
    unsigned o = (unsigned)__builtin_amdgcn_update_dpp((int)m, (int)m, CTRL, 0xF, 0xF, false);
    return (o > m) ? o : m;
}

template <int CTRL>
__device__ __forceinline__ u64 dpp_max_u64(u64 k)
{
    unsigned lo = (unsigned)k, hi = (unsigned)(k >> 32);
    unsigned olo = (unsigned)__builtin_amdgcn_update_dpp((int)lo, (int)lo, CTRL, 0xF, 0xF, false);
    unsigned ohi = (unsigned)__builtin_amdgcn_update_dpp((int)hi, (int)hi, CTRL, 0xF, 0xF, false);
    u64 o = ((u64)ohi << 32) | (u64)olo;
    return (o > k) ? o : k;
}

// ---------------------------------------------------------------- K1: fps (blocks 0..3) || phase A (blocks 4..131)
// fps scan loop: fma-form distance fma(dz,dz,fma(dy,dy,dx*dx)) (v2f -> pk_fma
// candidates), NO per-point tracking; running max(dist) chain only. Index
// recovered post-hoc: wave DPP max of dist bits -> all-lane DESCENDING rescan
// of 16 register dists for == max (first occurrence = smallest local index,
// uniform, no divergence) -> ballot lowest lane (= smallest global index via
// blocked ownership) -> readlane. Cross-wave: (bits, NP-1-idx) key as before.
// NOTE: fma-dist deviates from numpy by ~1-2 ulp relative; selections match
// unless a top-2 argmax margin is below that (calculated risk vs R12).
__global__ __launch_bounds__(512, 1) void k1_kernel(
    const float* __restrict__ xyz, const float* __restrict__ pts,
    float* __restrict__ newxyz,
    const float* __restrict__ w1, const float* __restrict__ b1,
    float* __restrict__ y1, float* __restrict__ st, unsigned* __restrict__ prog)
{
    __shared__ __align__(16) char smem[98432];
    const int tid = threadIdx.x;
    const int lane = tid & 63;
    const int wv = tid >> 6;                    // 8 waves

    if (blockIdx.x < NB) {
        // ======================= FPS path =======================
#pragma clang fp contract(off)
        float* s_px = (float*)smem;
        float* s_py = (float*)(smem + 32768);
        float* s_pz = (float*)(smem + 65536);
        u64*   s_kv = (u64*)(smem + 98304);     // [2][8]
        const int b = blockIdx.x;
        const float* xb = xyz + (size_t)b * NP * 3;

#pragma unroll
        for (int k = 0; k < 16; ++k) {
            const int i = k * 512 + tid;
            s_px[i] = xb[3 * i + 0];
            s_py[i] = xb[3 * i + 1];
            s_pz[i] = xb[3 * i + 2];
        }
        __syncthreads();

        v2f px[8], py[8], pz[8], dist[8];
        const int base = tid << 4;
#pragma unroll
        for (int m = 0; m < 8; ++m) {
            const int p0 = base + 2 * m;
            px[m] = v2f{s_px[p0], s_px[p0 + 1]};
            py[m] = v2f{s_py[p0], s_py[p0 + 1]};
            pz[m] = v2f{s_pz[p0], s_pz[p0 + 1]};
            dist[m] = v2f{1e10f, 1e10f};
        }
        float cx = s_px[0], cy = s_py[0], cz = s_pz[0];
        float* ob = newxyz + (size_t)b * NS * 3;

        for (int it = 0; it < NS; ++it) {
            if (tid == 0) {
                __hip_atomic_store(&prog[b], (unsigned)it, __ATOMIC_RELAXED, AGENT);
                __hip_atomic_store(&ob[it * 3 + 0], cx, __ATOMIC_RELAXED, AGENT);
                __hip_atomic_store(&ob[it * 3 + 1], cy, __ATOMIC_RELAXED, AGENT);
                __hip_atomic_store(&ob[it * 3 + 2], cz, __ATOMIC_RELAXED, AGENT);
            }
            const v2f cxx = v2f{cx, cx}, cyy = v2f{cy, cy}, czz = v2f{cz, cz};
            v2f bdv = v2f{-1.0f, -1.0f};
#pragma unroll
            for (int m = 0; m < 8; ++m) {
                v2f dx = px[m] - cxx, dy = py[m] - cyy, dz = pz[m] - czz;
                v2f d = __builtin_elementwise_fma(dz, dz,
                            __builtin_elementwise_fma(dy, dy, dx * dx));
                v2f dj = __builtin_elementwise_min(dist[m], d);
                dist[m] = dj;
                bdv = __builtin_elementwise_max(bdv, dj);
            }
            const float bd = fmaxf(bdv.x, bdv.y);
            // wave max of dist bits (bd >= 0 -> float bits order-preserving)
            const unsigned ub = __float_as_uint(bd);
            unsigned m0 = dpp_max_u32<0xB1>(ub);    // xor1
            m0 = dpp_max_u32<0x4E>(m0);             // xor2
            m0 = dpp_max_u32<0x141>(m0);            // row_half_mirror
            m0 = dpp_max_u32<0x140>(m0);            // row_mirror
            m0 = dpp_max_u32<0x142>(m0);            // row_bcast15
            m0 = dpp_max_u32<0x143>(m0);            // row_bcast31 -> lane63 = max
            const unsigned maxbits = (unsigned)__builtin_amdgcn_readlane((int)m0, 63);
            const float bdw = __uint_as_float(maxbits);
            // uniform all-lane descending rescan: smallest local j with dist==bdw
            int jb = 0;
#pragma unroll
            for (int m = 7; m >= 0; --m) {
                jb = (dist[m].y == bdw) ? (2 * m + 1) : jb;
                jb = (dist[m].x == bdw) ? (2 * m) : jb;
            }
            const u64 bm = __ballot(ub == maxbits);
            const int srclane = __ffsll(bm) - 1;    // lowest lane = lowest index
            const int wbi = __builtin_amdgcn_readlane(base + jb, srclane);
            if (lane == 0)
                s_kv[(it & 1) * 8 + wv] = ((u64)maxbits << 32) | (unsigned)(NP - 1 - wbi);
            __syncthreads();                      // drains centroid stores too
            u64 kv = s_kv[(it & 1) * 8 + (lane & 7)];
            kv = dpp_max_u64<0xB1>(kv);
            kv = dpp_max_u64<0x4E>(kv);
            kv = dpp_max_u64<0x141>(kv);
            const int fi = NP - 1 - (int)(unsigned)(kv & 0xFFFFFFFFull);
            cx = s_px[fi]; cy = s_py[fi]; cz = s_pz[fi];
        }
        if (tid == 0)
            __hip_atomic_store(&prog[b], (unsigned)NS, __ATOMIC_RELAXED, AGENT);
        return;
    }

    // ======================= Phase A path (R12-frozen) =======================
    int*   s_ball = (int*)smem;                    // [8][NK]
    float* s_cent = (float*)(smem + 1024);         // [8][4]
    float* s_feat = (float*)(smem + 1152);         // [256][20]
    float* s_ps   = (float*)(smem + 1152 + 20480); // [512]
    float* s_pq   = s_ps + 512;

    const int abk = blockIdx.x - NB;               // 0..127
    const int b = abk >> 5;                        // 32 blocks/batch
    const int s0 = (abk & 31) * 32;                // local centroid base
    const float* xb = xyz + (size_t)b * NP * 3;
    const float rr = (float)(0.2 * 0.2);

    const int c = tid & 63, rg = tid >> 6;
    float wvr[20];
#pragma unroll
    for (int j = 0; j < 19; ++j) wvr[j] = w1[c * 19 + j];
    wvr[19] = 0.f;
    const float bs = b1[c];
    float sa = 0.f, qa = 0.f;

    for (int chunk = 0; chunk < 4; ++chunk) {
        const int sl = s0 + chunk * 8;             // local centroid index of group 0
        if (tid == 0) {
            while ((int)__hip_atomic_load(&prog[b], __ATOMIC_RELAXED, AGENT) < sl + 8)
                __builtin_amdgcn_s_sleep(4);
        }
        __syncthreads();                            // wait done; s_ball/s_feat reusable
        // ---- ball query: wave wv -> group sl+wv
        {
            const int sg = (b << 10) + sl + wv;     // global group
            float cxv, cyv, czv;
            if (lane == 0) {
                cxv = __hip_atomic_load(&newxyz[sg * 3 + 0], __ATOMIC_RELAXED, AGENT);
                cyv = __hip_atomic_load(&newxyz[sg * 3 + 1], __ATOMIC_RELAXED, AGENT);
                czv = __hip_atomic_load(&newxyz[sg * 3 + 2], __ATOMIC_RELAXED, AGENT);
                s_cent[wv * 4 + 0] = cxv;
                s_cent[wv * 4 + 1] = cyv;
                s_cent[wv * 4 + 2] = czv;
            }
            cxv = __shfl(cxv, 0); cyv = __shfl(cyv, 0); czv = __shfl(czv, 0);
            int cnt = 0;
            for (int bse = 0; bse < NP && cnt < NK; bse += 64) {
                const int p = bse + lane;
                float dx = xb[p * 3 + 0] - cxv;
                float dy = xb[p * 3 + 1] - cyv;
                float dz = xb[p * 3 + 2] - czv;
                float d = __fadd_rn(__fadd_rn(__fmul_rn(dx, dx), __fmul_rn(dy, dy)),
                                    __fmul_rn(dz, dz));
                bool in = (d <= rr);
                u64 mask = __ballot(in);
                int before = __popcll(mask & ((1ull << lane) - 1ull));
                int pos = cnt + before;
                if (in && pos < NK) s_ball[wv * NK + pos] = p;
                cnt += (int)__popcll(mask);
            }
            cnt = min(cnt, NK);
            const int v0 = s_ball[wv * NK];         // cnt >= 1 (centroid in-radius)
            if (lane < NK && lane >= cnt) s_ball[wv * NK + lane] = v0;
        }
        __syncthreads();
        // ---- stage features (threads 0..255 -> rows 0..255)
        if (tid < 256) {
            const int lg = tid >> 5, k = tid & 31;
            const int id = s_ball[lg * NK + k];
            const float* pp = xyz + ((size_t)b * NP + id) * 3;
            float* f = s_feat + tid * 20;
            f[0] = pp[0] - s_cent[lg * 4 + 0];
            f[1] = pp[1] - s_cent[lg * 4 + 1];
            f[2] = pp[2] - s_cent[lg * 4 + 2];
            const float4* q4 = (const float4*)(pts + ((size_t)b * NP + id) * 16);
#pragma unroll
            for (int i = 0; i < 4; ++i) {
                float4 v = q4[i];
                f[3 + 4 * i + 0] = v.x; f[3 + 4 * i + 1] = v.y;
                f[3 + 4 * i + 2] = v.z; f[3 + 4 * i + 3] = v.w;
            }
            f[19] = 0.f;
        }
        __syncthreads();
        // ---- GEMV: thread owns channel c, rows rg*32..+31 of the 256 chunk rows
        const size_t rowbase = (size_t)abk * 1024 + (size_t)chunk * 256;
        for (int r = 0; r < 32; ++r) {
            const int row = rg * 32 + r;
            const float4* f4 = (const float4*)(s_feat + row * 20);
            float acc = bs;
#pragma unroll
            for (int j4 = 0; j4 < 5; ++j4) {
                float4 v = f4[j4];
                acc += wvr[4*j4+0]*v.x + wvr[4*j4+1]*v.y + wvr[4*j4+2]*v.z + wvr[4*j4+3]*v.w;
            }
            y1[(rowbase + row) * 64 + c] = acc;
            sa += acc; qa += acc * acc;
        }
        __syncthreads();                            // protect s_feat/s_ball for next chunk
    }
    s_ps[tid] = sa; s_pq[tid] = qa;
    __syncthreads();
    if (tid < 64) {
        float ts = 0.f, tq = 0.f;
#pragma unroll
        for (int i = 0; i < 8; ++i) { ts += s_ps[i * 64 + tid]; tq += s_pq[i * 64 + tid]; }
        atomicAdd(&st[(abk & 7) * 64 + tid], ts);          // sums1 shard
        atomicAdd(&st[512 + (abk & 7) * 64 + tid], tq);    // sqs1 shard
    }
}

// BN scale/shift for channel c from 8-sharded sums (cross-dispatch, plain loads)
__device__ __forceinline__ void bn_coef(const float* __restrict__ sums,
                                        const float* __restrict__ sqs,
                                        const float* __restrict__ g,
                                        const float* __restrict__ be,
                                        int C, int c, float& sc, float& sh)
{
    float s = 0.f, q = 0.f;
#pragma unroll
    for (int k = 0; k < 8; ++k) { s += sums[k * C + c]; q += sqs[k * C + c]; }
    const float mean = s / CNT_ALL;
    const float var = q / CNT_ALL - mean * mean;
    sc = g[c] / sqrtf(var + 1e-5f);
    sh = be[c] - mean * sc;
}

// ---------------------------------------------------------------- Phase B: BN1+ReLU + linear2 + stats2 (R7-validated)
__global__ __launch_bounds__(256) void phaseB_kernel(
    const float* __restrict__ y1,
    const float* __restrict__ g1, const float* __restrict__ be1,
    const float* __restrict__ w2, const float* __restrict__ b2,
    float* __restrict__ y2, float* __restrict__ st)
{
    __shared__ float x_lds[128 * 64];       // 32 KB
    __shared__ float s_sc[64], s_sh[64];
    __shared__ float s_ps[256], s_pq[256];
    const float* sums1 = st;
    const float* sqs1 = st + 512;
    float* sums2 = st + 1024;
    float* sqs2 = st + 1536;

    const int tid = threadIdx.x;
    const int bk = blockIdx.x;
    if (tid < 64) {
        float sc, sh;
        bn_coef(sums1, sqs1, g1, be1, 64, tid, sc, sh);
        s_sc[tid] = sc; s_sh[tid] = sh;
    }
    __syncthreads();
    const int c = tid & 63, rg = tid >> 6;
    float wv[64];
#pragma unroll
    for (int j = 0; j < 64; ++j) wv[j] = w2[c * 64 + j];
    const float bs = b2[c];
    float s = 0.f, q = 0.f;
    for (int half = 0; half < 2; ++half) {
        const size_t row0 = (size_t)256 * bk + 128 * half;
        const float4* y1g = (const float4*)(y1 + row0 * 64);
        float4* xl4 = (float4*)x_lds;
#pragma unroll
        for (int i = 0; i < 8; ++i) {
            const int slot = i * 256 + tid;
            float4 v = y1g[slot];
            const int c4 = (slot & 15) * 4;
            float4 o;
            o.x = fmaxf(v.x * s_sc[c4+0] + s_sh[c4+0], 0.f);
            o.y = fmaxf(v.y * s_sc[c4+1] + s_sh[c4+1], 0.f);
            o.z = fmaxf(v.z * s_sc[c4+2] + s_sh[c4+2], 0.f);
            o.w = fmaxf(v.w * s_sc[c4+3] + s_sh[c4+3], 0.f);
            xl4[slot] = o;
        }
        __syncthreads();
        for (int r = 0; r < 32; ++r) {
            const int row = rg * 32 + r;
            const float4* x4 = (const float4*)(x_lds + row * 64);
            float acc = bs;
#pragma unroll
            for (int j4 = 0; j4 < 16; ++j4) {
                float4 v = x4[j4];
                acc += wv[4*j4+0]*v.x + wv[4*j4+1]*v.y + wv[4*j4+2]*v.z + wv[4*j4+3]*v.w;
            }
            y2[(row0 + row) * 64 + c] = acc;
            s += acc; q += acc * acc;
        }
        __syncthreads();
    }
    s_ps[tid] = s; s_pq[tid] = q;
    __syncthreads();
    if (rg == 0) {
        float ts = s_ps[c] + s_ps[64 + c] + s_ps[128 + c] + s_ps[192 + c];
        float tq = s_pq[c] + s_pq[64 + c] + s_pq[128 + c] + s_pq[192 + c];
        atomicAdd(&sums2[(bk & 7) * 64 + c], ts);
        atomicAdd(&sqs2[(bk & 7) * 64 + c], tq);
    }
}

// ---------------------------------------------------------------- Phase C': BN2+ReLU + linear3 + stats3 + per-(g,c) max/min
__global__ __launch_bounds__(256) void phaseC2_kernel(
    const float* __restrict__ y2,
    const float* __restrict__ g2, const float* __restrict__ be2,
    const float* __restrict__ w3, const float* __restrict__ b3,
    float* __restrict__ st, float* __restrict__ mxb, float* __restrict__ mnb)
{
    __shared__ float s_x[NK * 64];          // 8 KB
    __shared__ float s_sc[64], s_sh[64];
    __shared__ float s_p3s[256], s_p3q[256];
    __shared__ float s_mx[256], s_mn[256];
    const float* sums2 = st + 1024;
    const float* sqs2 = st + 1536;
    float* sums3 = st + 2048;
    float* sqs3 = st + 3072;

    const int tid = threadIdx.x;
    const int bk = blockIdx.x;              // 512 blocks x 8 groups
    if (tid < 64) {
        float sc, sh;
        bn_coef(sums2, sqs2, g2, be2, 64, tid, sc, sh);
        s_sc[tid] = sc; s_sh[tid] = sh;
    }
    __syncthreads();
    const int c = tid & 127, rg = tid >> 7;
    float wv[64];
#pragma unroll
    for (int j = 0; j < 64; ++j) wv[j] = w3[c * 64 + j];
    const float bs = b3[c];
    float s = 0.f, q = 0.f;
    for (int gi = 0; gi < 8; ++gi) {
        const size_t grow0 = (size_t)256 * bk + 32 * gi;
        const float4* y2g = (const float4*)(y2 + grow0 * 64);
        float4* sx4 = (float4*)s_x;
#pragma unroll
        for (int i = 0; i < 2; ++i) {
            const int slot = i * 256 + tid;
            float4 v = y2g[slot];
            const int c4 = (slot & 15) * 4;
            float4 o;
            o.x = fmaxf(v.x * s_sc[c4+0] + s_sh[c4+0], 0.f);
            o.y = fmaxf(v.y * s_sc[c4+1] + s_sh[c4+1], 0.f);
            o.z = fmaxf(v.z * s_sc[c4+2] + s_sh[c4+2], 0.f);
            o.w = fmaxf(v.w * s_sc[c4+3] + s_sh[c4+3], 0.f);
            sx4[slot] = o;
        }
        __syncthreads();
        float mx = -1e30f, mn = 1e30f;
        for (int r = 0; r < 16; ++r) {
            const int row = rg * 16 + r;
            const float4* x4 = (const float4*)(s_x + row * 64);
            float acc = bs;
#pragma unroll
            for (int j4 = 0; j4 < 16; ++j4) {
                float4 v = x4[j4];
                acc += wv[4*j4+0]*v.x + wv[4*j4+1]*v.y + wv[4*j4+2]*v.z + wv[4*j4+3]*v.w;
            }
            s += acc; q += acc * acc;
            mx = fmaxf(mx, acc); mn = fminf(mn, acc);
        }
        s_mx[rg * 128 + c] = mx; s_mn[rg * 128 + c] = mn;
        __syncthreads();
        if (rg == 0) {
            const size_t gidx = (size_t)(8 * bk + gi) * 128 + c;
            mxb[gidx] = fmaxf(s_mx[c], s_mx[128 + c]);
            mnb[gidx] = fminf(s_mn[c], s_mn[128 + c]);
        }
        __syncthreads();
    }
    s_p3s[rg * 128 + c] = s; s_p3q[rg * 128 + c] = q;
    __syncthreads();
    if (rg == 0) {
        atomicAdd(&sums3[(bk & 7) * 128 + c], s_p3s[c] + s_p3s[128 + c]);
        atomicAdd(&sqs3[(bk & 7) * 128 + c], s_p3q[c] + s_p3q[128 + c]);
    }
}

// ---------------------------------------------------------------- Phase D': BN3+ReLU+maxpool via monotonicity (bit-exact)
__global__ __launch_bounds__(256) void phaseD2_kernel(
    const float* __restrict__ st,
    const float* __restrict__ g3, const float* __restrict__ be3,
    const float* __restrict__ mxb, const float* __restrict__ mnb,
    float* __restrict__ out_np)
{
    const int idx = blockIdx.x * 256 + threadIdx.x;   // < 524288
    const int c = idx & 127;
    float sc, sh;
    bn_coef(st + 2048, st + 3072, g3, be3, 128, c, sc, sh);
    const float sel = (sc >= 0.f) ? mxb[idx] : mnb[idx];
    out_np[idx] = fmaxf(sel * sc + sh, 0.f);
}

// ---------------------------------------------------------------- host launch
extern "C" void kernel_launch(void* const* d_in, const int* in_sizes, int n_in,
                              void* d_out, int out_size, void* d_ws, size_t ws_size,
                              hipStream_t stream)
{
    (void)in_sizes; (void)n_in; (void)out_size;
    const float* xyz = (const float*)d_in[0];
    const float* pts = (const float*)d_in[1];
    const float* w1 = (const float*)d_in[2];
    const float* b1 = (const float*)d_in[3];
    const float* g1 = (const float*)d_in[4];
    const float* be1 = (const float*)d_in[5];
    const float* w2 = (const float*)d_in[6];
    const float* b2 = (const float*)d_in[7];
    const float* g2 = (const float*)d_in[8];
    const float* be2 = (const float*)d_in[9];
    const float* w3 = (const float*)d_in[10];
    const float* b3 = (const float*)d_in[11];
    const float* g3 = (const float*)d_in[12];
    const float* be3 = (const float*)d_in[13];

    float* out = (float*)d_out;
    float* newxyz = out;              // 4*1024*3
    float* newpts = out + NB * NS * 3;

    float* y1 = (float*)d_ws;                          // 8388608 f32
    float* y2 = y1 + 8388608;
    float* st = y2 + 8388608;                          // 4096 stats
    unsigned* prog = (unsigned*)(st + 4096);           // 4 progress ctrs
    float* mxb = st + 4104;                            // 524288
    float* mnb = mxb + 524288;
    const size_t needed = (2ull * 8388608ull + 4104ull + 2ull * 524288ull) * 4ull;
    if (ws_size < needed) return;

    hipMemsetAsync(st, 0, (4096 + 8) * sizeof(float), stream);   // stats + prog
    k1_kernel<<<NB + 128, 512, 0, stream>>>(xyz, pts, newxyz, w1, b1, y1, st, prog);
    phaseB_kernel<<<512, 256, 0, stream>>>(y1, g1, be1, w2, b2, y2, st);
    phaseC2_kernel<<<512, 256, 0, stream>>>(y2, g2, be2, w3, b3, st, mxb, mnb);
    phaseD2_kernel<<<2048, 256, 0, stream>>>(st, g3, be3, mxb, mnb, newpts);
}